// Round 12
// baseline (888.551 us; speedup 1.0000x reference)
//
#include <hip/hip_runtime.h>
#include <hip/hip_bf16.h>
#include <stdint.h>

// ---------- types ----------
typedef __attribute__((ext_vector_type(8))) short short8;   // 8 bf16
typedef __attribute__((ext_vector_type(4))) short short4v;  // 4 bf16 (8 B)
typedef __attribute__((ext_vector_type(4))) float f32x4;
typedef __attribute__((ext_vector_type(4))) float fvec4;

__device__ __forceinline__ short f2bf(float f) {
  unsigned u = __builtin_bit_cast(unsigned, f);
  unsigned r = u + 0x7fffu + ((u >> 16) & 1u);
  return (short)(r >> 16);
}

__device__ __forceinline__ void gload_lds16(const void* g, void* l) {
  __builtin_amdgcn_global_load_lds(
      (const __attribute__((address_space(1))) void*)g,
      (__attribute__((address_space(3))) void*)l, 16, 0, 0);
}

// Problem: x[64,64,500,12], adj[500,500], W[64,576], b[64]; out[64,64,500,12]
// M = I + 0.125*adj. K-axis (k,w): 9*512 = 4608 = 72 kt-tiles of 64.
// Tiled operand layout: tile = [128 r][64 c] bf16, 16 KB, XOR pre-swizzled.
// k=0 B-tiles: identity chunks -> 66 of 72 kt iterated (zero I-tiles skipped).
// nchunk=16 keeps the Z chunk (113 MB) L3-resident (R10 regression: worth ~140us).
#define VP   512
#define TILE_SHORTS 8192
#define PANEL_TILES 72
#define NSTEP 66

__device__ __forceinline__ int tswz(int r, int c) {
  return r * 64 + ((((c >> 3) ^ (r & 7)) << 3) | (c & 7));
}

// ---------- kernel 1: M^0 (I), M^1 tiles, fp32 master, bf16 M1^T ----------
__global__ __launch_bounds__(256) void initM_kernel(const float* __restrict__ adj,
    float* __restrict__ Mpow, short* __restrict__ Mt, short* __restrict__ M1T) {
  int idx = blockIdx.x * 256 + threadIdx.x;
  int v = idx >> 9, w = idx & 511;
  float m = 0.f;
  if (v < 500 && w < 500) m = 0.125f * adj[v * 500 + w] + (v == w ? 1.f : 0.f);
  Mpow[idx] = m;
  M1T[(size_t)w * VP + v] = f2bf(m);
  int bx = v >> 7, r = v & 127, c = w & 63;
  int kt0 = (w >> 6), kt1 = 8 + (w >> 6);
  Mt[(size_t)(bx * PANEL_TILES + kt0) * TILE_SHORTS + tswz(r, c)] =
      f2bf((v == w && v < 500) ? 1.f : 0.f);
  Mt[(size_t)(bx * PANEL_TILES + kt1) * TILE_SHORTS + tswz(r, c)] = f2bf(m);
}

// ---------- kernel 2: P = src * M1 (B-frag = one short8 from M1T) ----------
__global__ __launch_bounds__(256) void powstep_kernel(const float* __restrict__ src,
    const short* __restrict__ M1T, float* __restrict__ dst,
    short* __restrict__ Mt, int kslice) {
  int tid = threadIdx.x, wv = tid >> 6, lane = tid & 63;
  int tile = blockIdx.x * 4 + wv;
  int tv = tile >> 5, tw = tile & 31;
  int row  = tv * 16 + (lane & 15);
  int colw = tw * 16 + (lane & 15);
  int kgrp = (lane >> 4) * 8;
  const short* mcol = M1T + (size_t)colw * VP;
  f32x4 acc = {0.f, 0.f, 0.f, 0.f};
  for (int k0 = 0; k0 < 512; k0 += 32) {
    int kc = k0 + kgrp;
    fvec4 f0 = *(const fvec4*)&src[row * VP + kc];
    fvec4 f1 = *(const fvec4*)&src[row * VP + kc + 4];
    short8 a;
    for (int t = 0; t < 4; ++t) { a[t] = f2bf(f0[t]); a[4 + t] = f2bf(f1[t]); }
    short8 b = *(const short8*)&mcol[kc];
    acc = __builtin_amdgcn_mfma_f32_16x16x32_bf16(a, b, acc, 0, 0, 0);
  }
  for (int r = 0; r < 4; ++r) {
    int i = (lane >> 4) * 4 + r;
    int vv = tv * 16 + i;
    float val = acc[r];
    dst[vv * VP + colw] = val;
    int bx = vv >> 7, rr = vv & 127, c = colw & 63;
    int kt = kslice * 8 + (colw >> 6);
    Mt[(size_t)(bx * PANEL_TILES + kt) * TILE_SHORTS + tswz(rr, c)] = f2bf(val);
  }
}

// ---------- kernel 2.5: x transpose: x[n,c,w,l] f32 -> xb[n,l,w512,c64] bf16 ----
__global__ __launch_bounds__(256) void xpose_kernel(const float* __restrict__ x,
    short* __restrict__ xb) {
  int t = threadIdx.x, wv = t >> 6, lane = t & 63;
  int p  = blockIdx.x & 1;          // c-half
  int w0 = (blockIdx.x >> 1) * 64;  // 0..448
  int n  = blockIdx.y;
  const float* xs = x + (size_t)n * 64 * 6000;
  __shared__ short xl[32 * 770];
  for (int ci = 0; ci < 8; ++ci) {
    int crow = wv * 8 + ci;
    int c = p * 32 + crow;
    for (int i = 0; i < 3; ++i) {
      int wl = (i * 64 + lane) * 4;
      int gwl = w0 * 12 + wl;
      fvec4 v = {0.f, 0.f, 0.f, 0.f};
      if (gwl + 3 < 6000) {
        v = *(const fvec4*)&xs[(size_t)c * 6000 + gwl];
      } else {
        for (int e = 0; e < 4; ++e)
          if (gwl + e < 6000) v[e] = xs[(size_t)c * 6000 + gwl + e];
      }
      for (int e = 0; e < 4; ++e) xl[crow * 770 + wl + e] = f2bf(v[e]);
    }
  }
  __syncthreads();
  for (int i = 0; i < 12; ++i) {
    int ct = i * 256 + t;
    int bl = ct & 3;
    int w_l = (ct >> 2) & 63;
    int l = ct >> 8;
    short8 s;
    for (int j = 0; j < 8; ++j)
      s[j] = xl[(bl * 8 + j) * 770 + w_l * 12 + l];
    size_t dst = ((size_t)(n * 12 + l) * 512 + w0 + w_l) * 64 + (p * 4 + bl) * 8;
    *(short8*)(xb + dst) = s;
  }
}

// ---------- kernel 3: Z build — pure-register GEMM from xb ----------
__global__ __launch_bounds__(256) void zbuild_kernel(const short* __restrict__ xb,
    const float* __restrict__ W, short* __restrict__ Zt, int n0) {
  int t = threadIdx.x, wv = t >> 6, lane = t & 63;
  int lh = blockIdx.x;
  int l = lh >> 1, wh = lh & 1;
  int nloc = blockIdx.y;
  int n = n0 + nloc;
  const short* xbase = xb + (size_t)(n * 12 + l) * 512 * 64;
  short8 af[4][2];
  for (int q = 0; q < 4; ++q)
    for (int ks = 0; ks < 2; ++ks) {
      int wrow = wh * 256 + wv * 64 + q * 16 + (lane & 15);
      int cblk = ks * 4 + (lane >> 4);
      af[q][ks] = *(const short8*)(xbase + (size_t)wrow * 64 + cblk * 8);
    }
  int lanebase = (lane & 15) * 12 + l;
  int kt_off = wh * 4 + wv;
  for (int j = 0; j < 36; ++j) {
    int k = j >> 2;
    int o = (j & 3) * 16 + (lane & 15);
    const float* wp = W + o * 576 + k * 64;
    short8 bw[2];
    for (int ks = 0; ks < 2; ++ks) {
      fvec4 f0 = *(const fvec4*)(wp + ks * 32 + (lane >> 4) * 8);
      fvec4 f1 = *(const fvec4*)(wp + ks * 32 + (lane >> 4) * 8 + 4);
      for (int e = 0; e < 4; ++e) { bw[ks][e] = f2bf(f0[e]); bw[ks][4 + e] = f2bf(f1[e]); }
    }
    f32x4 acc[4];
    for (int q = 0; q < 4; ++q) {
      acc[q] = (f32x4){0.f, 0.f, 0.f, 0.f};
      acc[q] = __builtin_amdgcn_mfma_f32_16x16x32_bf16(af[q][0], bw[0], acc[q], 0, 0, 0);
      acc[q] = __builtin_amdgcn_mfma_f32_16x16x32_bf16(af[q][1], bw[1], acc[q], 0, 0, 0);
    }
    int zr = (j & 3) * 192 + lanebase;
    int pr = zr >> 7, rr = zr & 127;
    size_t tbase = ((size_t)(nloc * 6 + pr) * PANEL_TILES + k * 8 + kt_off) * TILE_SHORTS
                 + rr * 64;
    for (int q = 0; q < 4; ++q) {
      int c4 = q * 16 + (lane >> 4) * 4;
      size_t idx = tbase + ((((c4 >> 3) ^ (zr & 7)) << 3) | (c4 & 7));
      short4v s;
      for (int e = 0; e < 4; ++e) s[e] = f2bf(acc[q][e]);
      *(short4v*)(Zt + idx) = s;
    }
  }
}

// ---------- kernel 4: big batched GEMM ----------
// Depth-3 pipeline, 4 LDS buffers, SINGLE barrier per K-step.
// Race-freedom of STAGE(s+3) into buf[(s+3)&3] == buf[(s-1)&3]: every wave's
// lgkmcnt(0) for its step-(s-1) reads precedes its arrival at step s's
// barrier, so at barrier-exit no pending reads exist on that buffer.
// vmcnt ladder: 16 (stages s+1,s+2 in flight) / 8 / 0 at the tail.
__global__ __launch_bounds__(256) void biggemm_kernel(const short* __restrict__ Zt,
    const short* __restrict__ Mt, const float* __restrict__ bvec,
    float* __restrict__ out, int n0) {
  int tid = threadIdx.x, wv = tid >> 6, lane = tid & 63;
  int nwg = gridDim.x;
  int b = blockIdx.x;
  int swz = (b & 7) * (nwg >> 3) + (b >> 3);   // nwg = 24*cn, always % 8 == 0
  int bx = swz & 3;
  int rest = swz >> 2;
  int by = rest % 6;
  int bz = rest / 6;
  int v0    = bx * 128;
  int rowM0 = by * 128;
  int n = n0 + bz;
  __shared__ short As[4][TILE_SHORTS];   // 4 x 16 KiB
  __shared__ short Bs[4][TILE_SHORTS];   // 4 x 16 KiB (128 KiB total, 1 blk/CU)
  f32x4 acc[4][4];
  for (int i = 0; i < 4; ++i)
    for (int j = 0; j < 4; ++j) acc[i][j] = (f32x4){0.f, 0.f, 0.f, 0.f};
  int wr = wv >> 1, wc = wv & 1;
  const char* Apanel = (const char*)(Zt + (size_t)(bz * 6 + by) * PANEL_TILES * TILE_SHORTS);
  const char* Bpanel = (const char*)(Mt + (size_t)bx * PANEL_TILES * TILE_SHORTS);

  // step -> kt: k=0 B-tiles are identity; only kt = bx*2, bx*2+1 nonzero.
  auto ktmap = [&](int s) { return (s < 2) ? (bx * 2 + s) : (s + 6); };

  auto STAGE = [&](int p, int kt) {
    const char* a  = Apanel + (size_t)kt * (TILE_SHORTS * 2);
    const char* bb = Bpanel + (size_t)kt * (TILE_SHORTS * 2);
#pragma unroll
    for (int cc = 0; cc < 4; ++cc) {
      int chunk = cc * 4 + wv;
      int off = chunk * 1024 + lane * 16;   // linear 1KB per instruction
      gload_lds16(a + off,  (char*)As[p] + chunk * 1024);
      gload_lds16(bb + off, (char*)Bs[p] + chunk * 1024);
    }
  };

  // prologue: three K-steps in flight (24 outstanding gloads/wave)
  STAGE(0, ktmap(0));
  STAGE(1, ktmap(1));
  STAGE(2, ktmap(2));

  for (int s = 0; s < NSTEP; ++s) {
    int d = s & 3;
    // wait for stage s; keep stages s+1, s+2 in flight (never 0 mid-loop)
    if (s < NSTEP - 2) {
      asm volatile("s_waitcnt vmcnt(16)" ::: "memory");
    } else if (s == NSTEP - 2) {
      asm volatile("s_waitcnt vmcnt(8)" ::: "memory");
    } else {
      asm volatile("s_waitcnt vmcnt(0)" ::: "memory");
    }
    __builtin_amdgcn_sched_barrier(0);
    __builtin_amdgcn_s_barrier();          // buf[d] ready AND buf[(d+3)&3] dead

    // refill the buffer freed at step s-1 (lands ~3 steps from now)
    if (s + 3 < NSTEP) STAGE((s + 3) & 3, ktmap(s + 3));

    // read ALL fragments for this K-step into registers
    short8 af[2][4], bf[2][4];
#pragma unroll
    for (int kk = 0; kk < 2; ++kk) {
      int cbyte = kk * 64 + (lane >> 4) * 16;
#pragma unroll
      for (int mi = 0; mi < 4; ++mi) {
        int r = wr * 64 + mi * 16 + (lane & 15);
        af[kk][mi] = *(const short8*)((const char*)As[d] + r * 128 + (cbyte ^ ((r & 7) << 4)));
      }
#pragma unroll
      for (int ni = 0; ni < 4; ++ni) {
        int r = wc * 64 + ni * 16 + (lane & 15);
        bf[kk][ni] = *(const short8*)((const char*)Bs[d] + r * 128 + (cbyte ^ ((r & 7) << 4)));
      }
    }
    asm volatile("s_waitcnt lgkmcnt(0)" ::: "memory");
    __builtin_amdgcn_sched_barrier(0);

    __builtin_amdgcn_s_setprio(1);
#pragma unroll
    for (int kk = 0; kk < 2; ++kk)
#pragma unroll
      for (int mi = 0; mi < 4; ++mi)
#pragma unroll
        for (int ni = 0; ni < 4; ++ni)
          acc[mi][ni] = __builtin_amdgcn_mfma_f32_16x16x32_bf16(af[kk][mi], bf[kk][ni],
                                                                acc[mi][ni], 0, 0, 0);
    __builtin_amdgcn_s_setprio(0);
  }

  for (int mi = 0; mi < 4; ++mi) {
    for (int r = 0; r < 4; ++r) {
      int gm = rowM0 + wr * 64 + mi * 16 + (lane >> 4) * 4 + r;
      int o = gm / 12, l = gm - o * 12;
      float bo = bvec[o];
      size_t obase = (((size_t)n * 64 + o) * 500) * 12 + l;
      for (int ni = 0; ni < 4; ++ni) {
        int v = v0 + wc * 64 + ni * 16 + (lane & 15);
        if (v < 500) out[obase + (size_t)v * 12] = acc[mi][ni][r] + bo;
      }
    }
  }
}

// ---------- host ----------
extern "C" void kernel_launch(void* const* d_in, const int* in_sizes, int n_in,
                              void* d_out, int out_size, void* d_ws, size_t ws_size,
                              hipStream_t stream) {
  const float* x   = (const float*)d_in[0];
  const float* adj = (const float*)d_in[1];
  const float* W   = (const float*)d_in[2];
  const float* bv  = (const float*)d_in[3];
  float* out = (float*)d_out;
  char* ws = (char*)d_ws;

  size_t off = 0;
  float* Mpow0 = (float*)(ws + off); off += (size_t)512 * 512 * 4;
  float* Mpow1 = (float*)(ws + off); off += (size_t)512 * 512 * 4;
  short* M1T   = (short*)(ws + off); off += (size_t)512 * 512 * 2;
  short* Mt    = (short*)(ws + off); off += (size_t)4 * PANEL_TILES * TILE_SHORTS * 2;
  short* xb    = (short*)(ws + off); off += (size_t)64 * 12 * 512 * 64 * 2;  // 50.3 MB
  short* Zt    = (short*)(ws + off);
  size_t per_n = (size_t)6 * PANEL_TILES * TILE_SHORTS * 2;          // 7,077,888 B
  int nchunk = 1;
  if (ws_size > off) {
    size_t a = (ws_size - off) / per_n;
    nchunk = (a >= 16) ? 16 : (a < 1 ? 1 : (int)a);   // 16 -> Z chunk 113 MB, L3-fits
  }

  hipLaunchKernelGGL(initM_kernel, dim3(1024), dim3(256), 0, stream, adj, Mpow0, Mt, M1T);
  const float* src = Mpow0; float* dst = Mpow1;
  for (int k = 2; k <= 8; ++k) {
    hipLaunchKernelGGL(powstep_kernel, dim3(256), dim3(256), 0, stream, src, M1T, dst, Mt, k);
    float* t = dst; dst = (float*)src; src = t;
  }
  hipLaunchKernelGGL(xpose_kernel, dim3(16, 64), dim3(256), 0, stream, x, xb);
  for (int n0 = 0; n0 < 64; n0 += nchunk) {
    int cn = (64 - n0) < nchunk ? (64 - n0) : nchunk;
    hipLaunchKernelGGL(zbuild_kernel, dim3(24, cn), dim3(256), 0, stream, xb, W, Zt, n0);
    hipLaunchKernelGGL(biggemm_kernel, dim3(24 * cn), dim3(256), 0, stream, Zt, Mt, bv, out, n0);
  }
}

// Round 13
// 695.191 us; speedup vs baseline: 1.2781x; 1.2781x over previous
//
#include <hip/hip_runtime.h>
#include <hip/hip_bf16.h>
#include <stdint.h>

// ---------- types ----------
typedef __attribute__((ext_vector_type(8))) short short8;   // 8 bf16
typedef __attribute__((ext_vector_type(4))) short short4v;  // 4 bf16 (8 B)
typedef __attribute__((ext_vector_type(4))) float f32x4;
typedef __attribute__((ext_vector_type(4))) float fvec4;

__device__ __forceinline__ short f2bf(float f) {
  unsigned u = __builtin_bit_cast(unsigned, f);
  unsigned r = u + 0x7fffu + ((u >> 16) & 1u);
  return (short)(r >> 16);
}

__device__ __forceinline__ void gload_lds16(const void* g, void* l) {
  __builtin_amdgcn_global_load_lds(
      (const __attribute__((address_space(1))) void*)g,
      (__attribute__((address_space(3))) void*)l, 16, 0, 0);
}

// Problem: x[64,64,500,12], adj[500,500], W[64,576], b[64]; out[64,64,500,12]
// M = I + 0.125*adj. K-axis (k,w): 9*512 = 4608 = 72 kt-tiles of 64.
// Tiled operand layout: tile = [128 r][64 c] bf16, 16 KB, XOR pre-swizzled.
// k=0 B-tiles: identity chunks -> 66 of 72 kt iterated.
// nchunk=16 keeps the Z chunk (113 MB) L3-resident (R10: worth ~140us).
// R12 lesson: >=2 blocks/CU is mandatory (1 blk/CU = 2x slower) -> LDS <= 64KB.
// This round: B operand bypasses LDS (per-lane dwordx4 from L2-hot Mt,
// register-double-buffered 1 step ahead) -> LDS 32KB, traffic halved.
#define VP   512
#define TILE_SHORTS 8192
#define PANEL_TILES 72
#define NSTEP 66

__device__ __forceinline__ int tswz(int r, int c) {
  return r * 64 + ((((c >> 3) ^ (r & 7)) << 3) | (c & 7));
}

// ---------- kernel 1: M^0 (I), M^1 tiles, fp32 master, bf16 M1^T ----------
__global__ __launch_bounds__(256) void initM_kernel(const float* __restrict__ adj,
    float* __restrict__ Mpow, short* __restrict__ Mt, short* __restrict__ M1T) {
  int idx = blockIdx.x * 256 + threadIdx.x;
  int v = idx >> 9, w = idx & 511;
  float m = 0.f;
  if (v < 500 && w < 500) m = 0.125f * adj[v * 500 + w] + (v == w ? 1.f : 0.f);
  Mpow[idx] = m;
  M1T[(size_t)w * VP + v] = f2bf(m);
  int bx = v >> 7, r = v & 127, c = w & 63;
  int kt0 = (w >> 6), kt1 = 8 + (w >> 6);
  Mt[(size_t)(bx * PANEL_TILES + kt0) * TILE_SHORTS + tswz(r, c)] =
      f2bf((v == w && v < 500) ? 1.f : 0.f);
  Mt[(size_t)(bx * PANEL_TILES + kt1) * TILE_SHORTS + tswz(r, c)] = f2bf(m);
}

// ---------- kernel 2: P = src * M1 (B-frag = one short8 from M1T) ----------
__global__ __launch_bounds__(256) void powstep_kernel(const float* __restrict__ src,
    const short* __restrict__ M1T, float* __restrict__ dst,
    short* __restrict__ Mt, int kslice) {
  int tid = threadIdx.x, wv = tid >> 6, lane = tid & 63;
  int tile = blockIdx.x * 4 + wv;
  int tv = tile >> 5, tw = tile & 31;
  int row  = tv * 16 + (lane & 15);
  int colw = tw * 16 + (lane & 15);
  int kgrp = (lane >> 4) * 8;
  const short* mcol = M1T + (size_t)colw * VP;
  f32x4 acc = {0.f, 0.f, 0.f, 0.f};
  for (int k0 = 0; k0 < 512; k0 += 32) {
    int kc = k0 + kgrp;
    fvec4 f0 = *(const fvec4*)&src[row * VP + kc];
    fvec4 f1 = *(const fvec4*)&src[row * VP + kc + 4];
    short8 a;
    for (int t = 0; t < 4; ++t) { a[t] = f2bf(f0[t]); a[4 + t] = f2bf(f1[t]); }
    short8 b = *(const short8*)&mcol[kc];
    acc = __builtin_amdgcn_mfma_f32_16x16x32_bf16(a, b, acc, 0, 0, 0);
  }
  for (int r = 0; r < 4; ++r) {
    int i = (lane >> 4) * 4 + r;
    int vv = tv * 16 + i;
    float val = acc[r];
    dst[vv * VP + colw] = val;
    int bx = vv >> 7, rr = vv & 127, c = colw & 63;
    int kt = kslice * 8 + (colw >> 6);
    Mt[(size_t)(bx * PANEL_TILES + kt) * TILE_SHORTS + tswz(rr, c)] = f2bf(val);
  }
}

// ---------- kernel 2.5: x transpose: x[n,c,w,l] f32 -> xb[n,l,w512,c64] bf16 ----
__global__ __launch_bounds__(256) void xpose_kernel(const float* __restrict__ x,
    short* __restrict__ xb) {
  int t = threadIdx.x, wv = t >> 6, lane = t & 63;
  int p  = blockIdx.x & 1;          // c-half
  int w0 = (blockIdx.x >> 1) * 64;  // 0..448
  int n  = blockIdx.y;
  const float* xs = x + (size_t)n * 64 * 6000;
  __shared__ short xl[32 * 770];
  for (int ci = 0; ci < 8; ++ci) {
    int crow = wv * 8 + ci;
    int c = p * 32 + crow;
    for (int i = 0; i < 3; ++i) {
      int wl = (i * 64 + lane) * 4;
      int gwl = w0 * 12 + wl;
      fvec4 v = {0.f, 0.f, 0.f, 0.f};
      if (gwl + 3 < 6000) {
        v = *(const fvec4*)&xs[(size_t)c * 6000 + gwl];
      } else {
        for (int e = 0; e < 4; ++e)
          if (gwl + e < 6000) v[e] = xs[(size_t)c * 6000 + gwl + e];
      }
      for (int e = 0; e < 4; ++e) xl[crow * 770 + wl + e] = f2bf(v[e]);
    }
  }
  __syncthreads();
  for (int i = 0; i < 12; ++i) {
    int ct = i * 256 + t;
    int bl = ct & 3;
    int w_l = (ct >> 2) & 63;
    int l = ct >> 8;
    short8 s;
    for (int j = 0; j < 8; ++j)
      s[j] = xl[(bl * 8 + j) * 770 + w_l * 12 + l];
    size_t dst = ((size_t)(n * 12 + l) * 512 + w0 + w_l) * 64 + (p * 4 + bl) * 8;
    *(short8*)(xb + dst) = s;
  }
}

// ---------- kernel 3: Z build — pure-register GEMM from xb ----------
__global__ __launch_bounds__(256) void zbuild_kernel(const short* __restrict__ xb,
    const float* __restrict__ W, short* __restrict__ Zt, int n0) {
  int t = threadIdx.x, wv = t >> 6, lane = t & 63;
  int lh = blockIdx.x;
  int l = lh >> 1, wh = lh & 1;
  int nloc = blockIdx.y;
  int n = n0 + nloc;
  const short* xbase = xb + (size_t)(n * 12 + l) * 512 * 64;
  short8 af[4][2];
  for (int q = 0; q < 4; ++q)
    for (int ks = 0; ks < 2; ++ks) {
      int wrow = wh * 256 + wv * 64 + q * 16 + (lane & 15);
      int cblk = ks * 4 + (lane >> 4);
      af[q][ks] = *(const short8*)(xbase + (size_t)wrow * 64 + cblk * 8);
    }
  int lanebase = (lane & 15) * 12 + l;
  int kt_off = wh * 4 + wv;
  for (int j = 0; j < 36; ++j) {
    int k = j >> 2;
    int o = (j & 3) * 16 + (lane & 15);
    const float* wp = W + o * 576 + k * 64;
    short8 bw[2];
    for (int ks = 0; ks < 2; ++ks) {
      fvec4 f0 = *(const fvec4*)(wp + ks * 32 + (lane >> 4) * 8);
      fvec4 f1 = *(const fvec4*)(wp + ks * 32 + (lane >> 4) * 8 + 4);
      for (int e = 0; e < 4; ++e) { bw[ks][e] = f2bf(f0[e]); bw[ks][4 + e] = f2bf(f1[e]); }
    }
    f32x4 acc[4];
    for (int q = 0; q < 4; ++q) {
      acc[q] = (f32x4){0.f, 0.f, 0.f, 0.f};
      acc[q] = __builtin_amdgcn_mfma_f32_16x16x32_bf16(af[q][0], bw[0], acc[q], 0, 0, 0);
      acc[q] = __builtin_amdgcn_mfma_f32_16x16x32_bf16(af[q][1], bw[1], acc[q], 0, 0, 0);
    }
    int zr = (j & 3) * 192 + lanebase;
    int pr = zr >> 7, rr = zr & 127;
    size_t tbase = ((size_t)(nloc * 6 + pr) * PANEL_TILES + k * 8 + kt_off) * TILE_SHORTS
                 + rr * 64;
    for (int q = 0; q < 4; ++q) {
      int c4 = q * 16 + (lane >> 4) * 4;
      size_t idx = tbase + ((((c4 >> 3) ^ (zr & 7)) << 3) | (c4 & 7));
      short4v s;
      for (int e = 0; e < 4; ++e) s[e] = f2bf(acc[q][e]);
      *(short4v*)(Zt + idx) = s;
    }
  }
}

// ---------- kernel 4: big batched GEMM ----------
// A: LDS double-buffer via global_load_lds (32 KB). B: per-lane dwordx4 from
// L2-hot Mt, register-dbuf'd one step ahead (bfA/bfB, 2-step-unrolled loop).
// vmcnt invariant at step-top: queue = [B(s) x8, A(s+1) x4] -> vmcnt(4)
// drains B(s)+A(s), keeps A(s+1) in flight. Issue order per step:
// BLOAD(s+1) ... barrier ... STAGE_A(s+2) preserves it.
__global__ __launch_bounds__(256) void biggemm_kernel(const short* __restrict__ Zt,
    const short* __restrict__ Mt, const float* __restrict__ bvec,
    float* __restrict__ out, int n0) {
  int tid = threadIdx.x, wv = tid >> 6, lane = tid & 63;
  int nwg = gridDim.x;
  int b = blockIdx.x;
  int swz = (b & 7) * (nwg >> 3) + (b >> 3);   // nwg = 24*cn, always % 8 == 0
  int bx = swz & 3;
  int rest = swz >> 2;
  int by = rest % 6;
  int bz = rest / 6;
  int v0    = bx * 128;
  int rowM0 = by * 128;
  int n = n0 + bz;
  __shared__ short As[2][TILE_SHORTS];   // 2 x 16 KiB = 32 KiB total
  f32x4 acc[4][4];
  for (int i = 0; i < 4; ++i)
    for (int j = 0; j < 4; ++j) acc[i][j] = (f32x4){0.f, 0.f, 0.f, 0.f};
  int wr = wv >> 1, wc = wv & 1;
  const char* Apanel = (const char*)(Zt + (size_t)(bz * 6 + by) * PANEL_TILES * TILE_SHORTS);
  const char* Bpanel = (const char*)(Mt + (size_t)bx * PANEL_TILES * TILE_SHORTS);

  // step -> kt: k=0 B-tiles are identity; only kt = bx*2, bx*2+1 nonzero.
  auto ktmap = [&](int s) { return (s < 2) ? (bx * 2 + s) : (s + 6); };

  auto STAGE_A = [&](int p, int kt) {
    const char* a = Apanel + (size_t)kt * (TILE_SHORTS * 2);
#pragma unroll
    for (int cc = 0; cc < 4; ++cc) {
      int chunk = cc * 4 + wv;
      int off = chunk * 1024 + lane * 16;   // linear 1KB per instruction
      gload_lds16(a + off, (char*)As[p] + chunk * 1024);
    }
  };

  // Per-lane B addressing into the pre-swizzled global tile:
  // byte = kt*16384 + r*128 + (cbyte ^ ((r&7)<<4)),
  // r = wc*64 + ni*16 + (lane&15), cbyte = kk*64 + (lane>>4)*16.
  const char* Bgbase = Bpanel + (lane & 15) * 128 + wc * 8192;
  int offk0 = (((lane >> 4) * 16)      ^ ((lane & 7) << 4));
  int offk1 = ((64 + (lane >> 4) * 16) ^ ((lane & 7) << 4));
  auto BLOAD = [&](int kt, short8 (&bfn)[2][4]) {
    const char* p0 = Bgbase + (size_t)kt * (TILE_SHORTS * 2) + offk0;
    const char* p1 = Bgbase + (size_t)kt * (TILE_SHORTS * 2) + offk1;
#pragma unroll
    for (int ni = 0; ni < 4; ++ni) {
      bfn[0][ni] = *(const short8*)(p0 + ni * 2048);
      bfn[1][ni] = *(const short8*)(p1 + ni * 2048);
    }
  };

  short8 bfA[2][4], bfB[2][4];

  auto STEP = [&](int s, short8 (&bfc)[2][4], short8 (&bfn)[2][4]) {
    int d = s & 1;
    if (s < NSTEP - 1) {
      asm volatile("s_waitcnt vmcnt(4)" ::: "memory");
    } else {
      asm volatile("s_waitcnt vmcnt(0)" ::: "memory");
    }
    __builtin_amdgcn_sched_barrier(0);
    __builtin_amdgcn_s_barrier();          // As[d] visible to all waves
    if (s + 1 < NSTEP) BLOAD(ktmap(s + 1), bfn);
    __builtin_amdgcn_sched_barrier(0);
    short8 af[2][4];
#pragma unroll
    for (int kk = 0; kk < 2; ++kk) {
      int cbyte = kk * 64 + (lane >> 4) * 16;
#pragma unroll
      for (int mi = 0; mi < 4; ++mi) {
        int r = wr * 64 + mi * 16 + (lane & 15);
        af[kk][mi] = *(const short8*)((const char*)As[d] + r * 128 + (cbyte ^ ((r & 7) << 4)));
      }
    }
    asm volatile("s_waitcnt lgkmcnt(0)" ::: "memory");
    __builtin_amdgcn_sched_barrier(0);
    __builtin_amdgcn_s_barrier();          // all waves done reading As[d]
    if (s + 2 < NSTEP) STAGE_A(d, ktmap(s + 2));
    __builtin_amdgcn_s_setprio(1);
#pragma unroll
    for (int kk = 0; kk < 2; ++kk)
#pragma unroll
      for (int mi = 0; mi < 4; ++mi)
#pragma unroll
        for (int ni = 0; ni < 4; ++ni)
          acc[mi][ni] = __builtin_amdgcn_mfma_f32_16x16x32_bf16(af[kk][mi], bfc[kk][ni],
                                                                acc[mi][ni], 0, 0, 0);
    __builtin_amdgcn_s_setprio(0);
  };

  // prologue order matters for the vmcnt FIFO invariant: A0, B0, A1
  STAGE_A(0, ktmap(0));
  BLOAD(ktmap(0), bfA);
  STAGE_A(1, ktmap(1));

  for (int ss = 0; ss < NSTEP; ss += 2) {
    STEP(ss,     bfA, bfB);
    STEP(ss + 1, bfB, bfA);
  }

  for (int mi = 0; mi < 4; ++mi) {
    for (int r = 0; r < 4; ++r) {
      int gm = rowM0 + wr * 64 + mi * 16 + (lane >> 4) * 4 + r;
      int o = gm / 12, l = gm - o * 12;
      float bo = bvec[o];
      size_t obase = (((size_t)n * 64 + o) * 500) * 12 + l;
      for (int ni = 0; ni < 4; ++ni) {
        int v = v0 + wc * 64 + ni * 16 + (lane & 15);
        if (v < 500) out[obase + (size_t)v * 12] = acc[mi][ni][r] + bo;
      }
    }
  }
}

// ---------- host ----------
extern "C" void kernel_launch(void* const* d_in, const int* in_sizes, int n_in,
                              void* d_out, int out_size, void* d_ws, size_t ws_size,
                              hipStream_t stream) {
  const float* x   = (const float*)d_in[0];
  const float* adj = (const float*)d_in[1];
  const float* W   = (const float*)d_in[2];
  const float* bv  = (const float*)d_in[3];
  float* out = (float*)d_out;
  char* ws = (char*)d_ws;

  size_t off = 0;
  float* Mpow0 = (float*)(ws + off); off += (size_t)512 * 512 * 4;
  float* Mpow1 = (float*)(ws + off); off += (size_t)512 * 512 * 4;
  short* M1T   = (short*)(ws + off); off += (size_t)512 * 512 * 2;
  short* Mt    = (short*)(ws + off); off += (size_t)4 * PANEL_TILES * TILE_SHORTS * 2;
  short* xb    = (short*)(ws + off); off += (size_t)64 * 12 * 512 * 64 * 2;  // 50.3 MB
  short* Zt    = (short*)(ws + off);
  size_t per_n = (size_t)6 * PANEL_TILES * TILE_SHORTS * 2;          // 7,077,888 B
  int nchunk = 1;
  if (ws_size > off) {
    size_t a = (ws_size - off) / per_n;
    nchunk = (a >= 16) ? 16 : (a < 1 ? 1 : (int)a);   // 16 -> Z chunk 113 MB, L3-fits
  }

  hipLaunchKernelGGL(initM_kernel, dim3(1024), dim3(256), 0, stream, adj, Mpow0, Mt, M1T);
  const float* src = Mpow0; float* dst = Mpow1;
  for (int k = 2; k <= 8; ++k) {
    hipLaunchKernelGGL(powstep_kernel, dim3(256), dim3(256), 0, stream, src, M1T, dst, Mt, k);
    float* t = dst; dst = (float*)src; src = t;
  }
  hipLaunchKernelGGL(xpose_kernel, dim3(16, 64), dim3(256), 0, stream, x, xb);
  for (int n0 = 0; n0 < 64; n0 += nchunk) {
    int cn = (64 - n0) < nchunk ? (64 - n0) : nchunk;
    hipLaunchKernelGGL(zbuild_kernel, dim3(24, cn), dim3(256), 0, stream, xb, W, Zt, n0);
    hipLaunchKernelGGL(biggemm_kernel, dim3(24 * cn), dim3(256), 0, stream, Zt, Mt, bv, out, n0);
  }
}

// Round 14
// 589.129 us; speedup vs baseline: 1.5082x; 1.1800x over previous
//
#include <hip/hip_runtime.h>
#include <hip/hip_bf16.h>
#include <stdint.h>

// ---------- types ----------
typedef __attribute__((ext_vector_type(8))) short short8;   // 8 bf16
typedef __attribute__((ext_vector_type(4))) short short4v;  // 4 bf16 (8 B)
typedef __attribute__((ext_vector_type(4))) float f32x4;
typedef __attribute__((ext_vector_type(4))) float fvec4;

__device__ __forceinline__ short f2bf(float f) {
  unsigned u = __builtin_bit_cast(unsigned, f);
  unsigned r = u + 0x7fffu + ((u >> 16) & 1u);
  return (short)(r >> 16);
}

__device__ __forceinline__ void gload_lds16(const void* g, void* l) {
  __builtin_amdgcn_global_load_lds(
      (const __attribute__((address_space(1))) void*)g,
      (__attribute__((address_space(3))) void*)l, 16, 0, 0);
}

// Problem: x[64,64,500,12], adj[500,500], W[64,576], b[64]; out[64,64,500,12]
// M = I + 0.125*adj. K-axis (k,w): 9*512 = 4608 = 72 kt-tiles of 64.
// Tiled operand layout: tile = [128 r][64 c] bf16, 16 KB, XOR pre-swizzled.
// nchunk=16 keeps the Z chunk (113 MB) L3-resident (R10: worth ~140us).
// R12/R13 lessons: >=2 blocks/CU mandatory; both operands via global_load_lds;
// counted vmcnt 2-deep. This round: v-tile 128->64 (8 bx) -> grid 768 = 3
// blocks/CU, LDS 48KB, 6 loads/stage, and k=0 identity hits exactly ONE kt
// per block -> NSTEP 65.
#define VP   512
#define TILE_SHORTS 8192
#define PANEL_TILES 72
#define NSTEP 65

__device__ __forceinline__ int tswz(int r, int c) {
  return r * 64 + ((((c >> 3) ^ (r & 7)) << 3) | (c & 7));
}

// ---------- kernel 1: M^0 (I), M^1 tiles, fp32 master, bf16 M1^T ----------
__global__ __launch_bounds__(256) void initM_kernel(const float* __restrict__ adj,
    float* __restrict__ Mpow, short* __restrict__ Mt, short* __restrict__ M1T) {
  int idx = blockIdx.x * 256 + threadIdx.x;
  int v = idx >> 9, w = idx & 511;
  float m = 0.f;
  if (v < 500 && w < 500) m = 0.125f * adj[v * 500 + w] + (v == w ? 1.f : 0.f);
  Mpow[idx] = m;
  M1T[(size_t)w * VP + v] = f2bf(m);
  int bx = v >> 7, r = v & 127, c = w & 63;
  int kt0 = (w >> 6), kt1 = 8 + (w >> 6);
  Mt[(size_t)(bx * PANEL_TILES + kt0) * TILE_SHORTS + tswz(r, c)] =
      f2bf((v == w && v < 500) ? 1.f : 0.f);
  Mt[(size_t)(bx * PANEL_TILES + kt1) * TILE_SHORTS + tswz(r, c)] = f2bf(m);
}

// ---------- kernel 2: P = src * M1 (B-frag = one short8 from M1T) ----------
__global__ __launch_bounds__(256) void powstep_kernel(const float* __restrict__ src,
    const short* __restrict__ M1T, float* __restrict__ dst,
    short* __restrict__ Mt, int kslice) {
  int tid = threadIdx.x, wv = tid >> 6, lane = tid & 63;
  int tile = blockIdx.x * 4 + wv;
  int tv = tile >> 5, tw = tile & 31;
  int row  = tv * 16 + (lane & 15);
  int colw = tw * 16 + (lane & 15);
  int kgrp = (lane >> 4) * 8;
  const short* mcol = M1T + (size_t)colw * VP;
  f32x4 acc = {0.f, 0.f, 0.f, 0.f};
  for (int k0 = 0; k0 < 512; k0 += 32) {
    int kc = k0 + kgrp;
    fvec4 f0 = *(const fvec4*)&src[row * VP + kc];
    fvec4 f1 = *(const fvec4*)&src[row * VP + kc + 4];
    short8 a;
    for (int t = 0; t < 4; ++t) { a[t] = f2bf(f0[t]); a[4 + t] = f2bf(f1[t]); }
    short8 b = *(const short8*)&mcol[kc];
    acc = __builtin_amdgcn_mfma_f32_16x16x32_bf16(a, b, acc, 0, 0, 0);
  }
  for (int r = 0; r < 4; ++r) {
    int i = (lane >> 4) * 4 + r;
    int vv = tv * 16 + i;
    float val = acc[r];
    dst[vv * VP + colw] = val;
    int bx = vv >> 7, rr = vv & 127, c = colw & 63;
    int kt = kslice * 8 + (colw >> 6);
    Mt[(size_t)(bx * PANEL_TILES + kt) * TILE_SHORTS + tswz(rr, c)] = f2bf(val);
  }
}

// ---------- kernel 2.5: x transpose: x[n,c,w,l] f32 -> xb[n,l,w512,c64] bf16 ----
__global__ __launch_bounds__(256) void xpose_kernel(const float* __restrict__ x,
    short* __restrict__ xb) {
  int t = threadIdx.x, wv = t >> 6, lane = t & 63;
  int p  = blockIdx.x & 1;          // c-half
  int w0 = (blockIdx.x >> 1) * 64;  // 0..448
  int n  = blockIdx.y;
  const float* xs = x + (size_t)n * 64 * 6000;
  __shared__ short xl[32 * 770];
  for (int ci = 0; ci < 8; ++ci) {
    int crow = wv * 8 + ci;
    int c = p * 32 + crow;
    for (int i = 0; i < 3; ++i) {
      int wl = (i * 64 + lane) * 4;
      int gwl = w0 * 12 + wl;
      fvec4 v = {0.f, 0.f, 0.f, 0.f};
      if (gwl + 3 < 6000) {
        v = *(const fvec4*)&xs[(size_t)c * 6000 + gwl];
      } else {
        for (int e = 0; e < 4; ++e)
          if (gwl + e < 6000) v[e] = xs[(size_t)c * 6000 + gwl + e];
      }
      for (int e = 0; e < 4; ++e) xl[crow * 770 + wl + e] = f2bf(v[e]);
    }
  }
  __syncthreads();
  for (int i = 0; i < 12; ++i) {
    int ct = i * 256 + t;
    int bl = ct & 3;
    int w_l = (ct >> 2) & 63;
    int l = ct >> 8;
    short8 s;
    for (int j = 0; j < 8; ++j)
      s[j] = xl[(bl * 8 + j) * 770 + w_l * 12 + l];
    size_t dst = ((size_t)(n * 12 + l) * 512 + w0 + w_l) * 64 + (p * 4 + bl) * 8;
    *(short8*)(xb + dst) = s;
  }
}

// ---------- kernel 3: Z build — pure-register GEMM from xb ----------
__global__ __launch_bounds__(256) void zbuild_kernel(const short* __restrict__ xb,
    const float* __restrict__ W, short* __restrict__ Zt, int n0) {
  int t = threadIdx.x, wv = t >> 6, lane = t & 63;
  int lh = blockIdx.x;
  int l = lh >> 1, wh = lh & 1;
  int nloc = blockIdx.y;
  int n = n0 + nloc;
  const short* xbase = xb + (size_t)(n * 12 + l) * 512 * 64;
  short8 af[4][2];
  for (int q = 0; q < 4; ++q)
    for (int ks = 0; ks < 2; ++ks) {
      int wrow = wh * 256 + wv * 64 + q * 16 + (lane & 15);
      int cblk = ks * 4 + (lane >> 4);
      af[q][ks] = *(const short8*)(xbase + (size_t)wrow * 64 + cblk * 8);
    }
  int lanebase = (lane & 15) * 12 + l;
  int kt_off = wh * 4 + wv;
  for (int j = 0; j < 36; ++j) {
    int k = j >> 2;
    int o = (j & 3) * 16 + (lane & 15);
    const float* wp = W + o * 576 + k * 64;
    short8 bw[2];
    for (int ks = 0; ks < 2; ++ks) {
      fvec4 f0 = *(const fvec4*)(wp + ks * 32 + (lane >> 4) * 8);
      fvec4 f1 = *(const fvec4*)(wp + ks * 32 + (lane >> 4) * 8 + 4);
      for (int e = 0; e < 4; ++e) { bw[ks][e] = f2bf(f0[e]); bw[ks][4 + e] = f2bf(f1[e]); }
    }
    f32x4 acc[4];
    for (int q = 0; q < 4; ++q) {
      acc[q] = (f32x4){0.f, 0.f, 0.f, 0.f};
      acc[q] = __builtin_amdgcn_mfma_f32_16x16x32_bf16(af[q][0], bw[0], acc[q], 0, 0, 0);
      acc[q] = __builtin_amdgcn_mfma_f32_16x16x32_bf16(af[q][1], bw[1], acc[q], 0, 0, 0);
    }
    int zr = (j & 3) * 192 + lanebase;
    int pr = zr >> 7, rr = zr & 127;
    size_t tbase = ((size_t)(nloc * 6 + pr) * PANEL_TILES + k * 8 + kt_off) * TILE_SHORTS
                 + rr * 64;
    for (int q = 0; q < 4; ++q) {
      int c4 = q * 16 + (lane >> 4) * 4;
      size_t idx = tbase + ((((c4 >> 3) ^ (zr & 7)) << 3) | (c4 & 7));
      short4v s;
      for (int e = 0; e < 4; ++e) s[e] = f2bf(acc[q][e]);
      *(short4v*)(Zt + idx) = s;
    }
  }
}

// ---------- kernel 4: big batched GEMM ----------
// R11 pipeline (2 LDS dbufs, counted vmcnt, 2 barriers/step, setprio MFMA),
// retiled: output 128 x 64 per block (8 bx v-tiles), 4 waves each 32x64.
// Per stage: A 16KB (4 gloads/wave) + B half-tile 8KB (2 gloads/wave) = 6.
// LDS 48KB -> 3 blocks/CU; grid 768 -> full 3/CU supply.
__global__ __launch_bounds__(256) void biggemm_kernel(const short* __restrict__ Zt,
    const short* __restrict__ Mt, const float* __restrict__ bvec,
    float* __restrict__ out, int n0) {
  int tid = threadIdx.x, wv = tid >> 6, lane = tid & 63;
  int nwg = gridDim.x;
  int b = blockIdx.x;
  int swz = (b & 7) * (nwg >> 3) + (b >> 3);   // nwg = 48*cn, always % 8 == 0
  int bx = swz & 7;                // v-tile of 64, fastest (8 siblings share A)
  int rest = swz >> 3;
  int by = rest % 6;
  int bz = rest / 6;
  int v0    = bx * 64;
  int rowM0 = by * 128;
  int n = n0 + bz;
  __shared__ short As[2][TILE_SHORTS];       // 2 x 16 KiB
  __shared__ short Bs[2][TILE_SHORTS / 2];   // 2 x 8 KiB  (48 KiB total)
  f32x4 acc[2][4];
  for (int i = 0; i < 2; ++i)
    for (int j = 0; j < 4; ++j) acc[i][j] = (f32x4){0.f, 0.f, 0.f, 0.f};
  const char* Apanel = (const char*)(Zt + (size_t)(bz * 6 + by) * PANEL_TILES * TILE_SHORTS);
  // B half-tile: rows [ (bx&1)*64, +64 ) of Mt tile (bx>>1, kt) = 8KB at
  // byte offset (bx&1)*8192 within the 16KB tile.
  const char* Bpanel = (const char*)(Mt + (size_t)(bx >> 1) * PANEL_TILES * TILE_SHORTS)
                     + (bx & 1) * 8192;

  // step -> kt: k=0 B-rows are identity; for this block's v-range only
  // kt == bx (w-range == v-range) is nonzero. Steps 1.. cover kt 8..71.
  auto ktmap = [&](int s) { return (s == 0) ? bx : (s + 7); };

  auto STAGE = [&](int p, int kt) {
    const char* a  = Apanel + (size_t)kt * (TILE_SHORTS * 2);
    const char* bb = Bpanel + (size_t)kt * (TILE_SHORTS * 2);
#pragma unroll
    for (int cc = 0; cc < 4; ++cc) {
      int chunk = cc * 4 + wv;                 // 0..15
      int off = chunk * 1024 + lane * 16;      // linear 1KB per instruction
      gload_lds16(a + off, (char*)As[p] + chunk * 1024);
    }
#pragma unroll
    for (int cc = 0; cc < 2; ++cc) {
      int chunk = cc * 4 + wv;                 // 0..7
      int off = chunk * 1024 + lane * 16;
      gload_lds16(bb + off, (char*)Bs[p] + chunk * 1024);
    }
  };

  // prologue: two K-steps in flight (12 outstanding gloads/wave)
  STAGE(0, ktmap(0));
  STAGE(1, ktmap(1));

  for (int s = 0; s < NSTEP; ++s) {
    int d = s & 1;
    // wait step s's 6 loads; keep s+1's 6 in flight (never 0 mid-loop)
    if (s < NSTEP - 1) {
      asm volatile("s_waitcnt vmcnt(6)" ::: "memory");
    } else {
      asm volatile("s_waitcnt vmcnt(0)" ::: "memory");
    }
    __builtin_amdgcn_sched_barrier(0);
    __builtin_amdgcn_s_barrier();          // dbuf[d] visible to all waves

    // read ALL fragments for this K-step into registers
    short8 af[2][2], bf[2][4];
#pragma unroll
    for (int kk = 0; kk < 2; ++kk) {
      int cbyte = kk * 64 + (lane >> 4) * 16;
#pragma unroll
      for (int mi = 0; mi < 2; ++mi) {
        int r = wv * 32 + mi * 16 + (lane & 15);
        af[kk][mi] = *(const short8*)((const char*)As[d] + r * 128 + (cbyte ^ ((r & 7) << 4)));
      }
#pragma unroll
      for (int ni = 0; ni < 4; ++ni) {
        int r2 = ni * 16 + (lane & 15);
        bf[kk][ni] = *(const short8*)((const char*)Bs[d] + r2 * 128 + (cbyte ^ ((r2 & 7) << 4)));
      }
    }
    asm volatile("s_waitcnt lgkmcnt(0)" ::: "memory");   // this wave's reads done
    __builtin_amdgcn_sched_barrier(0);
    __builtin_amdgcn_s_barrier();          // ALL waves' reads done -> dbuf[d] dead

    // issue next-next K-step into the freed buffer; lands under MFMA
    if (s + 2 < NSTEP) STAGE(d, ktmap(s + 2));

    __builtin_amdgcn_s_setprio(1);
#pragma unroll
    for (int kk = 0; kk < 2; ++kk)
#pragma unroll
      for (int mi = 0; mi < 2; ++mi)
#pragma unroll
        for (int ni = 0; ni < 4; ++ni)
          acc[mi][ni] = __builtin_amdgcn_mfma_f32_16x16x32_bf16(af[kk][mi], bf[kk][ni],
                                                                acc[mi][ni], 0, 0, 0);
    __builtin_amdgcn_s_setprio(0);
  }

  for (int mi = 0; mi < 2; ++mi) {
    for (int r = 0; r < 4; ++r) {
      int gm = rowM0 + wv * 32 + mi * 16 + (lane >> 4) * 4 + r;   // = o*12+l
      int o = gm / 12, l = gm - o * 12;
      float bo = bvec[o];
      size_t obase = (((size_t)n * 64 + o) * 500) * 12 + l;
      for (int ni = 0; ni < 4; ++ni) {
        int v = v0 + ni * 16 + (lane & 15);
        if (v < 500) out[obase + (size_t)v * 12] = acc[mi][ni][r] + bo;
      }
    }
  }
}

// ---------- host ----------
extern "C" void kernel_launch(void* const* d_in, const int* in_sizes, int n_in,
                              void* d_out, int out_size, void* d_ws, size_t ws_size,
                              hipStream_t stream) {
  const float* x   = (const float*)d_in[0];
  const float* adj = (const float*)d_in[1];
  const float* W   = (const float*)d_in[2];
  const float* bv  = (const float*)d_in[3];
  float* out = (float*)d_out;
  char* ws = (char*)d_ws;

  size_t off = 0;
  float* Mpow0 = (float*)(ws + off); off += (size_t)512 * 512 * 4;
  float* Mpow1 = (float*)(ws + off); off += (size_t)512 * 512 * 4;
  short* M1T   = (short*)(ws + off); off += (size_t)512 * 512 * 2;
  short* Mt    = (short*)(ws + off); off += (size_t)4 * PANEL_TILES * TILE_SHORTS * 2;
  short* xb    = (short*)(ws + off); off += (size_t)64 * 12 * 512 * 64 * 2;  // 50.3 MB
  short* Zt    = (short*)(ws + off);
  size_t per_n = (size_t)6 * PANEL_TILES * TILE_SHORTS * 2;          // 7,077,888 B
  int nchunk = 1;
  if (ws_size > off) {
    size_t a = (ws_size - off) / per_n;
    nchunk = (a >= 16) ? 16 : (a < 1 ? 1 : (int)a);   // 16 -> Z chunk 113 MB, L3-fits
  }

  hipLaunchKernelGGL(initM_kernel, dim3(1024), dim3(256), 0, stream, adj, Mpow0, Mt, M1T);
  const float* src = Mpow0; float* dst = Mpow1;
  for (int k = 2; k <= 8; ++k) {
    hipLaunchKernelGGL(powstep_kernel, dim3(256), dim3(256), 0, stream, src, M1T, dst, Mt, k);
    float* t = dst; dst = (float*)src; src = t;
  }
  hipLaunchKernelGGL(xpose_kernel, dim3(16, 64), dim3(256), 0, stream, x, xb);
  for (int n0 = 0; n0 < 64; n0 += nchunk) {
    int cn = (64 - n0) < nchunk ? (64 - n0) : nchunk;
    hipLaunchKernelGGL(zbuild_kernel, dim3(24, cn), dim3(256), 0, stream, xb, W, Zt, n0);
    hipLaunchKernelGGL(biggemm_kernel, dim3(48 * cn), dim3(256), 0, stream, Zt, Mt, bv, out, n0);
  }
}

// Round 15
// 586.033 us; speedup vs baseline: 1.5162x; 1.0053x over previous
//
#include <hip/hip_runtime.h>
#include <hip/hip_bf16.h>
#include <stdint.h>

// ---------- types ----------
typedef __attribute__((ext_vector_type(8))) short short8;   // 8 bf16
typedef __attribute__((ext_vector_type(4))) short short4v;  // 4 bf16 (8 B)
typedef __attribute__((ext_vector_type(4))) float f32x4;
typedef __attribute__((ext_vector_type(4))) float fvec4;

__device__ __forceinline__ short f2bf(float f) {
  unsigned u = __builtin_bit_cast(unsigned, f);
  unsigned r = u + 0x7fffu + ((u >> 16) & 1u);
  return (short)(r >> 16);
}

__device__ __forceinline__ void gload_lds16(const void* g, void* l) {
  __builtin_amdgcn_global_load_lds(
      (const __attribute__((address_space(1))) void*)g,
      (__attribute__((address_space(3))) void*)l, 16, 0, 0);
}

// Problem: x[64,64,500,12], adj[500,500], W[64,576], b[64]; out[64,64,500,12]
// M = I + 0.125*adj. K-axis (k,w): 9*512 = 4608 = 72 kt-tiles of 64.
// Tiled operand layout: tile = [128 r][64 c] bf16, 16 KB, XOR pre-swizzled.
// nchunk=16 keeps the Z chunk (113 MB) L3-resident (R10: worth ~140us).
// R14 finding: biggemm is LDS-BW-saturated (72KB/block-step = 288cy vs 283
// available). This round: K split across wave pairs -> wave tile 64x64x32,
// frag reads 48->32KB/step (-22% LDS); f32 k-half reduction in LDS epilogue.
#define VP   512
#define TILE_SHORTS 8192
#define PANEL_TILES 72
#define NSTEP 65

__device__ __forceinline__ int tswz(int r, int c) {
  return r * 64 + ((((c >> 3) ^ (r & 7)) << 3) | (c & 7));
}

// ---------- kernel 1: M^0 (I), M^1 tiles, fp32 master, bf16 M1^T ----------
__global__ __launch_bounds__(256) void initM_kernel(const float* __restrict__ adj,
    float* __restrict__ Mpow, short* __restrict__ Mt, short* __restrict__ M1T) {
  int idx = blockIdx.x * 256 + threadIdx.x;
  int v = idx >> 9, w = idx & 511;
  float m = 0.f;
  if (v < 500 && w < 500) m = 0.125f * adj[v * 500 + w] + (v == w ? 1.f : 0.f);
  Mpow[idx] = m;
  M1T[(size_t)w * VP + v] = f2bf(m);
  int bx = v >> 7, r = v & 127, c = w & 63;
  int kt0 = (w >> 6), kt1 = 8 + (w >> 6);
  Mt[(size_t)(bx * PANEL_TILES + kt0) * TILE_SHORTS + tswz(r, c)] =
      f2bf((v == w && v < 500) ? 1.f : 0.f);
  Mt[(size_t)(bx * PANEL_TILES + kt1) * TILE_SHORTS + tswz(r, c)] = f2bf(m);
}

// ---------- kernel 2: P = src * M1 (B-frag = one short8 from M1T) ----------
__global__ __launch_bounds__(256) void powstep_kernel(const float* __restrict__ src,
    const short* __restrict__ M1T, float* __restrict__ dst,
    short* __restrict__ Mt, int kslice) {
  int tid = threadIdx.x, wv = tid >> 6, lane = tid & 63;
  int tile = blockIdx.x * 4 + wv;
  int tv = tile >> 5, tw = tile & 31;
  int row  = tv * 16 + (lane & 15);
  int colw = tw * 16 + (lane & 15);
  int kgrp = (lane >> 4) * 8;
  const short* mcol = M1T + (size_t)colw * VP;
  f32x4 acc = {0.f, 0.f, 0.f, 0.f};
  for (int k0 = 0; k0 < 512; k0 += 32) {
    int kc = k0 + kgrp;
    fvec4 f0 = *(const fvec4*)&src[row * VP + kc];
    fvec4 f1 = *(const fvec4*)&src[row * VP + kc + 4];
    short8 a;
    for (int t = 0; t < 4; ++t) { a[t] = f2bf(f0[t]); a[4 + t] = f2bf(f1[t]); }
    short8 b = *(const short8*)&mcol[kc];
    acc = __builtin_amdgcn_mfma_f32_16x16x32_bf16(a, b, acc, 0, 0, 0);
  }
  for (int r = 0; r < 4; ++r) {
    int i = (lane >> 4) * 4 + r;
    int vv = tv * 16 + i;
    float val = acc[r];
    dst[vv * VP + colw] = val;
    int bx = vv >> 7, rr = vv & 127, c = colw & 63;
    int kt = kslice * 8 + (colw >> 6);
    Mt[(size_t)(bx * PANEL_TILES + kt) * TILE_SHORTS + tswz(rr, c)] = f2bf(val);
  }
}

// ---------- kernel 2.5: x transpose: x[n,c,w,l] f32 -> xb[n,l,w512,c64] bf16 ----
__global__ __launch_bounds__(256) void xpose_kernel(const float* __restrict__ x,
    short* __restrict__ xb) {
  int t = threadIdx.x, wv = t >> 6, lane = t & 63;
  int p  = blockIdx.x & 1;          // c-half
  int w0 = (blockIdx.x >> 1) * 64;  // 0..448
  int n  = blockIdx.y;
  const float* xs = x + (size_t)n * 64 * 6000;
  __shared__ short xl[32 * 770];
  for (int ci = 0; ci < 8; ++ci) {
    int crow = wv * 8 + ci;
    int c = p * 32 + crow;
    for (int i = 0; i < 3; ++i) {
      int wl = (i * 64 + lane) * 4;
      int gwl = w0 * 12 + wl;
      fvec4 v = {0.f, 0.f, 0.f, 0.f};
      if (gwl + 3 < 6000) {
        v = *(const fvec4*)&xs[(size_t)c * 6000 + gwl];
      } else {
        for (int e = 0; e < 4; ++e)
          if (gwl + e < 6000) v[e] = xs[(size_t)c * 6000 + gwl + e];
      }
      for (int e = 0; e < 4; ++e) xl[crow * 770 + wl + e] = f2bf(v[e]);
    }
  }
  __syncthreads();
  for (int i = 0; i < 12; ++i) {
    int ct = i * 256 + t;
    int bl = ct & 3;
    int w_l = (ct >> 2) & 63;
    int l = ct >> 8;
    short8 s;
    for (int j = 0; j < 8; ++j)
      s[j] = xl[(bl * 8 + j) * 770 + w_l * 12 + l];
    size_t dst = ((size_t)(n * 12 + l) * 512 + w0 + w_l) * 64 + (p * 4 + bl) * 8;
    *(short8*)(xb + dst) = s;
  }
}

// ---------- kernel 3: Z build — pure-register GEMM from xb ----------
__global__ __launch_bounds__(256) void zbuild_kernel(const short* __restrict__ xb,
    const float* __restrict__ W, short* __restrict__ Zt, int n0) {
  int t = threadIdx.x, wv = t >> 6, lane = t & 63;
  int lh = blockIdx.x;
  int l = lh >> 1, wh = lh & 1;
  int nloc = blockIdx.y;
  int n = n0 + nloc;
  const short* xbase = xb + (size_t)(n * 12 + l) * 512 * 64;
  short8 af[4][2];
  for (int q = 0; q < 4; ++q)
    for (int ks = 0; ks < 2; ++ks) {
      int wrow = wh * 256 + wv * 64 + q * 16 + (lane & 15);
      int cblk = ks * 4 + (lane >> 4);
      af[q][ks] = *(const short8*)(xbase + (size_t)wrow * 64 + cblk * 8);
    }
  int lanebase = (lane & 15) * 12 + l;
  int kt_off = wh * 4 + wv;
  for (int j = 0; j < 36; ++j) {
    int k = j >> 2;
    int o = (j & 3) * 16 + (lane & 15);
    const float* wp = W + o * 576 + k * 64;
    short8 bw[2];
    for (int ks = 0; ks < 2; ++ks) {
      fvec4 f0 = *(const fvec4*)(wp + ks * 32 + (lane >> 4) * 8);
      fvec4 f1 = *(const fvec4*)(wp + ks * 32 + (lane >> 4) * 8 + 4);
      for (int e = 0; e < 4; ++e) { bw[ks][e] = f2bf(f0[e]); bw[ks][4 + e] = f2bf(f1[e]); }
    }
    f32x4 acc[4];
    for (int q = 0; q < 4; ++q) {
      acc[q] = (f32x4){0.f, 0.f, 0.f, 0.f};
      acc[q] = __builtin_amdgcn_mfma_f32_16x16x32_bf16(af[q][0], bw[0], acc[q], 0, 0, 0);
      acc[q] = __builtin_amdgcn_mfma_f32_16x16x32_bf16(af[q][1], bw[1], acc[q], 0, 0, 0);
    }
    int zr = (j & 3) * 192 + lanebase;
    int pr = zr >> 7, rr = zr & 127;
    size_t tbase = ((size_t)(nloc * 6 + pr) * PANEL_TILES + k * 8 + kt_off) * TILE_SHORTS
                 + rr * 64;
    for (int q = 0; q < 4; ++q) {
      int c4 = q * 16 + (lane >> 4) * 4;
      size_t idx = tbase + ((((c4 >> 3) ^ (zr & 7)) << 3) | (c4 & 7));
      short4v s;
      for (int e = 0; e < 4; ++e) s[e] = f2bf(acc[q][e]);
      *(short4v*)(Zt + idx) = s;
    }
  }
}

// ---------- kernel 4: big batched GEMM (K-split across wave pairs) ----------
// Block: 128 rowM x 64 v, 4 waves. Wave (wr=wv&1, wk=wv>>1) computes rows
// [wr*64,+64) x all 64 v for k-half wk (32 of 64 K per step). Frag reads:
// A 4KB + B 4KB per wave per step (A read exactly once block-wide).
// Epilogue: wk=1 waves deposit f32 partials in LDS (stride-65 pad), wk=0 add.
// Pipeline (2 dbuf, counted vmcnt(6), 2 barriers/step, setprio) = R14.
__global__ __launch_bounds__(256) void biggemm_kernel(const short* __restrict__ Zt,
    const short* __restrict__ Mt, const float* __restrict__ bvec,
    float* __restrict__ out, int n0) {
  int tid = threadIdx.x, wv = tid >> 6, lane = tid & 63;
  int nwg = gridDim.x;
  int b = blockIdx.x;
  int swz = (b & 7) * (nwg >> 3) + (b >> 3);   // nwg = 48*cn, always % 8 == 0
  int bx = swz & 7;                // v-tile of 64, fastest (8 siblings share A)
  int rest = swz >> 3;
  int by = rest % 6;
  int bz = rest / 6;
  int v0    = bx * 64;
  int rowM0 = by * 128;
  int n = n0 + bz;
  int wr = wv & 1, wk = wv >> 1;
  __shared__ short lds[3 * TILE_SHORTS];      // 48 KiB pool
  short* Asp0 = lds;                          // As dbuf: 2 x 16 KiB
  short* Bsp0 = lds + 2 * TILE_SHORTS;        // Bs dbuf: 2 x 8 KiB
  f32x4 acc[4][4];
  for (int i = 0; i < 4; ++i)
    for (int j = 0; j < 4; ++j) acc[i][j] = (f32x4){0.f, 0.f, 0.f, 0.f};
  const char* Apanel = (const char*)(Zt + (size_t)(bz * 6 + by) * PANEL_TILES * TILE_SHORTS);
  const char* Bpanel = (const char*)(Mt + (size_t)(bx >> 1) * PANEL_TILES * TILE_SHORTS)
                     + (bx & 1) * 8192;

  // step -> kt: k=0 B-rows identity; only kt == bx nonzero for this v-range.
  auto ktmap = [&](int s) { return (s == 0) ? bx : (s + 7); };

  auto STAGE = [&](int p, int kt) {
    const char* a  = Apanel + (size_t)kt * (TILE_SHORTS * 2);
    const char* bb = Bpanel + (size_t)kt * (TILE_SHORTS * 2);
    char* asd = (char*)(Asp0 + p * TILE_SHORTS);
    char* bsd = (char*)(Bsp0 + p * (TILE_SHORTS / 2));
#pragma unroll
    for (int cc = 0; cc < 4; ++cc) {
      int chunk = cc * 4 + wv;                 // 0..15
      int off = chunk * 1024 + lane * 16;      // linear 1KB per instruction
      gload_lds16(a + off, asd + chunk * 1024);
    }
#pragma unroll
    for (int cc = 0; cc < 2; ++cc) {
      int chunk = cc * 4 + wv;                 // 0..7
      int off = chunk * 1024 + lane * 16;
      gload_lds16(bb + off, bsd + chunk * 1024);
    }
  };

  // prologue: two K-steps in flight (12 outstanding gloads/wave)
  STAGE(0, ktmap(0));
  STAGE(1, ktmap(1));

  int cbyte = wk * 64 + (lane >> 4) * 16;      // this wave's k-half columns

  for (int s = 0; s < NSTEP; ++s) {
    int d = s & 1;
    if (s < NSTEP - 1) {
      asm volatile("s_waitcnt vmcnt(6)" ::: "memory");
    } else {
      asm volatile("s_waitcnt vmcnt(0)" ::: "memory");
    }
    __builtin_amdgcn_sched_barrier(0);
    __builtin_amdgcn_s_barrier();          // dbuf[d] visible to all waves

    const char* asd = (const char*)(Asp0 + d * TILE_SHORTS);
    const char* bsd = (const char*)(Bsp0 + d * (TILE_SHORTS / 2));
    short8 af[4], bf[4];
#pragma unroll
    for (int mi = 0; mi < 4; ++mi) {
      int r = wr * 64 + mi * 16 + (lane & 15);
      af[mi] = *(const short8*)(asd + r * 128 + (cbyte ^ ((r & 7) << 4)));
    }
#pragma unroll
    for (int ni = 0; ni < 4; ++ni) {
      int r2 = ni * 16 + (lane & 15);
      bf[ni] = *(const short8*)(bsd + r2 * 128 + (cbyte ^ ((r2 & 7) << 4)));
    }
    asm volatile("s_waitcnt lgkmcnt(0)" ::: "memory");   // this wave's reads done
    __builtin_amdgcn_sched_barrier(0);
    __builtin_amdgcn_s_barrier();          // ALL waves' reads done -> dbuf[d] dead

    if (s + 2 < NSTEP) STAGE(d, ktmap(s + 2));

    __builtin_amdgcn_s_setprio(1);
#pragma unroll
    for (int mi = 0; mi < 4; ++mi)
#pragma unroll
      for (int ni = 0; ni < 4; ++ni)
        acc[mi][ni] = __builtin_amdgcn_mfma_f32_16x16x32_bf16(af[mi], bf[ni],
                                                              acc[mi][ni], 0, 0, 0);
    __builtin_amdgcn_s_setprio(0);
  }

  // ---- k-half reduction: wk=1 deposits partials; wk=0 adds + stores ----
  float* red = (float*)lds;                 // 128 x 65 f32 = 33.3 KB (fits 48K)
  __syncthreads();                          // main-loop LDS dead; safe to reuse
  if (wk) {
#pragma unroll
    for (int mi = 0; mi < 4; ++mi)
#pragma unroll
      for (int r = 0; r < 4; ++r) {
        int row = wr * 64 + mi * 16 + (lane >> 4) * 4 + r;
#pragma unroll
        for (int ni = 0; ni < 4; ++ni)
          red[row * 65 + ni * 16 + (lane & 15)] = acc[mi][ni][r];
      }
  }
  __syncthreads();
  if (!wk) {
    for (int mi = 0; mi < 4; ++mi) {
      for (int r = 0; r < 4; ++r) {
        int row = wr * 64 + mi * 16 + (lane >> 4) * 4 + r;
        int gm = rowM0 + row;                // = o*12+l
        int o = gm / 12, l = gm - o * 12;
        float bo = bvec[o];
        size_t obase = (((size_t)n * 64 + o) * 500) * 12 + l;
        for (int ni = 0; ni < 4; ++ni) {
          int v = v0 + ni * 16 + (lane & 15);
          if (v < 500)
            out[obase + (size_t)v * 12] =
                acc[mi][ni][r] + red[row * 65 + ni * 16 + (lane & 15)] + bo;
        }
      }
    }
  }
}

// ---------- host ----------
extern "C" void kernel_launch(void* const* d_in, const int* in_sizes, int n_in,
                              void* d_out, int out_size, void* d_ws, size_t ws_size,
                              hipStream_t stream) {
  const float* x   = (const float*)d_in[0];
  const float* adj = (const float*)d_in[1];
  const float* W   = (const float*)d_in[2];
  const float* bv  = (const float*)d_in[3];
  float* out = (float*)d_out;
  char* ws = (char*)d_ws;

  size_t off = 0;
  float* Mpow0 = (float*)(ws + off); off += (size_t)512 * 512 * 4;
  float* Mpow1 = (float*)(ws + off); off += (size_t)512 * 512 * 4;
  short* M1T   = (short*)(ws + off); off += (size_t)512 * 512 * 2;
  short* Mt    = (short*)(ws + off); off += (size_t)4 * PANEL_TILES * TILE_SHORTS * 2;
  short* xb    = (short*)(ws + off); off += (size_t)64 * 12 * 512 * 64 * 2;  // 50.3 MB
  short* Zt    = (short*)(ws + off);
  size_t per_n = (size_t)6 * PANEL_TILES * TILE_SHORTS * 2;          // 7,077,888 B
  int nchunk = 1;
  if (ws_size > off) {
    size_t a = (ws_size - off) / per_n;
    nchunk = (a >= 16) ? 16 : (a < 1 ? 1 : (int)a);   // 16 -> Z chunk 113 MB, L3-fits
  }

  hipLaunchKernelGGL(initM_kernel, dim3(1024), dim3(256), 0, stream, adj, Mpow0, Mt, M1T);
  const float* src = Mpow0; float* dst = Mpow1;
  for (int k = 2; k <= 8; ++k) {
    hipLaunchKernelGGL(powstep_kernel, dim3(256), dim3(256), 0, stream, src, M1T, dst, Mt, k);
    float* t = dst; dst = (float*)src; src = t;
  }
  hipLaunchKernelGGL(xpose_kernel, dim3(16, 64), dim3(256), 0, stream, x, xb);
  for (int n0 = 0; n0 < 64; n0 += nchunk) {
    int cn = (64 - n0) < nchunk ? (64 - n0) : nchunk;
    hipLaunchKernelGGL(zbuild_kernel, dim3(24, cn), dim3(256), 0, stream, xb, W, Zt, n0);
    hipLaunchKernelGGL(biggemm_kernel, dim3(48 * cn), dim3(256), 0, stream, Zt, Mt, bv, out, n0);
  }
}

// Round 16
// 509.293 us; speedup vs baseline: 1.7447x; 1.1507x over previous
//
#include <hip/hip_runtime.h>
#include <hip/hip_bf16.h>
#include <stdint.h>

// ---------- types ----------
typedef __attribute__((ext_vector_type(8))) short short8;   // 8 bf16
typedef __attribute__((ext_vector_type(4))) short short4v;  // 4 bf16 (8 B)
typedef __attribute__((ext_vector_type(4))) float f32x4;
typedef __attribute__((ext_vector_type(4))) float fvec4;

__device__ __forceinline__ short f2bf(float f) {
  unsigned u = __builtin_bit_cast(unsigned, f);
  unsigned r = u + 0x7fffu + ((u >> 16) & 1u);
  return (short)(r >> 16);
}

__device__ __forceinline__ void gload_lds16(const void* g, void* l) {
  __builtin_amdgcn_global_load_lds(
      (const __attribute__((address_space(1))) void*)g,
      (__attribute__((address_space(3))) void*)l, 16, 0, 0);
}

// Problem: x[64,64,500,12], adj[500,500], W[64,576], b[64]; out[64,64,500,12]
// M = I + 0.125*adj. K-axis (k,w): 9*512 = 4608 = 72 kt-tiles of 64.
// Tiled operand layout: tile = [128 r][64 c] bf16, 16 KB, XOR pre-swizzled.
// nchunk=16 keeps the Z chunk (113 MB) L3-resident (R10: worth ~140us).
// Biggemm = R14-proven config: v-tile 64 (8 bx), 4 waves x (32rowM x 64v),
// acc[2][4] (32 VGPR - no spill; R15's acc[4][4] spilled), LDS 48KB -> 3
// blocks/CU, counted vmcnt(6), NSTEP 65 (identity-tile skip).
// This round: zbuild de-VALU'd via pre-packed bf16 W (wprep) + j-split.
#define VP   512
#define TILE_SHORTS 8192
#define PANEL_TILES 72
#define NSTEP 65

__device__ __forceinline__ int tswz(int r, int c) {
  return r * 64 + ((((c >> 3) ^ (r & 7)) << 3) | (c & 7));
}

// ---------- kernel 1: M^0 (I), M^1 tiles, fp32 master, bf16 M1^T ----------
__global__ __launch_bounds__(256) void initM_kernel(const float* __restrict__ adj,
    float* __restrict__ Mpow, short* __restrict__ Mt, short* __restrict__ M1T) {
  int idx = blockIdx.x * 256 + threadIdx.x;
  int v = idx >> 9, w = idx & 511;
  float m = 0.f;
  if (v < 500 && w < 500) m = 0.125f * adj[v * 500 + w] + (v == w ? 1.f : 0.f);
  Mpow[idx] = m;
  M1T[(size_t)w * VP + v] = f2bf(m);
  int bx = v >> 7, r = v & 127, c = w & 63;
  int kt0 = (w >> 6), kt1 = 8 + (w >> 6);
  Mt[(size_t)(bx * PANEL_TILES + kt0) * TILE_SHORTS + tswz(r, c)] =
      f2bf((v == w && v < 500) ? 1.f : 0.f);
  Mt[(size_t)(bx * PANEL_TILES + kt1) * TILE_SHORTS + tswz(r, c)] = f2bf(m);
}

// ---------- kernel 1.5: W -> bf16 fragment-layout pack ----------
// Wbf[k][jm][ks][h4][l4][e8]: = f2bf(W[(jm*16+l4)*576 + k*64+ks*32+h*8+e])
__global__ __launch_bounds__(256) void wprep_kernel(const float* __restrict__ W,
    short* __restrict__ Wbf) {
  int idx = blockIdx.x * 256 + threadIdx.x;   // 0..36863 (grid 144)
  int e = idx & 7, l4 = (idx >> 3) & 15, h = (idx >> 7) & 3;
  int ks = (idx >> 9) & 1, jm = (idx >> 10) & 3, k = idx >> 12;
  int o = jm * 16 + l4, c = k * 64 + ks * 32 + h * 8 + e;
  Wbf[idx] = f2bf(W[o * 576 + c]);
}

// ---------- kernel 2: P = src * M1 (B-frag = one short8 from M1T) ----------
__global__ __launch_bounds__(256) void powstep_kernel(const float* __restrict__ src,
    const short* __restrict__ M1T, float* __restrict__ dst,
    short* __restrict__ Mt, int kslice) {
  int tid = threadIdx.x, wv = tid >> 6, lane = tid & 63;
  int tile = blockIdx.x * 4 + wv;
  int tv = tile >> 5, tw = tile & 31;
  int row  = tv * 16 + (lane & 15);
  int colw = tw * 16 + (lane & 15);
  int kgrp = (lane >> 4) * 8;
  const short* mcol = M1T + (size_t)colw * VP;
  f32x4 acc = {0.f, 0.f, 0.f, 0.f};
  for (int k0 = 0; k0 < 512; k0 += 32) {
    int kc = k0 + kgrp;
    fvec4 f0 = *(const fvec4*)&src[row * VP + kc];
    fvec4 f1 = *(const fvec4*)&src[row * VP + kc + 4];
    short8 a;
    for (int t = 0; t < 4; ++t) { a[t] = f2bf(f0[t]); a[4 + t] = f2bf(f1[t]); }
    short8 b = *(const short8*)&mcol[kc];
    acc = __builtin_amdgcn_mfma_f32_16x16x32_bf16(a, b, acc, 0, 0, 0);
  }
  for (int r = 0; r < 4; ++r) {
    int i = (lane >> 4) * 4 + r;
    int vv = tv * 16 + i;
    float val = acc[r];
    dst[vv * VP + colw] = val;
    int bx = vv >> 7, rr = vv & 127, c = colw & 63;
    int kt = kslice * 8 + (colw >> 6);
    Mt[(size_t)(bx * PANEL_TILES + kt) * TILE_SHORTS + tswz(rr, c)] = f2bf(val);
  }
}

// ---------- kernel 2.5: x transpose: x[n,c,w,l] f32 -> xb[n,l,w512,c64] bf16 ----
__global__ __launch_bounds__(256) void xpose_kernel(const float* __restrict__ x,
    short* __restrict__ xb) {
  int t = threadIdx.x, wv = t >> 6, lane = t & 63;
  int p  = blockIdx.x & 1;          // c-half
  int w0 = (blockIdx.x >> 1) * 64;  // 0..448
  int n  = blockIdx.y;
  const float* xs = x + (size_t)n * 64 * 6000;
  __shared__ short xl[32 * 770];
  for (int ci = 0; ci < 8; ++ci) {
    int crow = wv * 8 + ci;
    int c = p * 32 + crow;
    for (int i = 0; i < 3; ++i) {
      int wl = (i * 64 + lane) * 4;
      int gwl = w0 * 12 + wl;
      fvec4 v = {0.f, 0.f, 0.f, 0.f};
      if (gwl + 3 < 6000) {
        v = *(const fvec4*)&xs[(size_t)c * 6000 + gwl];
      } else {
        for (int e = 0; e < 4; ++e)
          if (gwl + e < 6000) v[e] = xs[(size_t)c * 6000 + gwl + e];
      }
      for (int e = 0; e < 4; ++e) xl[crow * 770 + wl + e] = f2bf(v[e]);
    }
  }
  __syncthreads();
  for (int i = 0; i < 12; ++i) {
    int ct = i * 256 + t;
    int bl = ct & 3;
    int w_l = (ct >> 2) & 63;
    int l = ct >> 8;
    short8 s;
    for (int j = 0; j < 8; ++j)
      s[j] = xl[(bl * 8 + j) * 770 + w_l * 12 + l];
    size_t dst = ((size_t)(n * 12 + l) * 512 + w0 + w_l) * 64 + (p * 4 + bl) * 8;
    *(short8*)(xb + dst) = s;
  }
}

// ---------- kernel 3: Z build — register GEMM, pre-packed W, j-split ----------
__global__ __launch_bounds__(256) void zbuild_kernel(const short* __restrict__ xb,
    const short* __restrict__ Wbf, short* __restrict__ Zt, int n0) {
  int t = threadIdx.x, wv = t >> 6, lane = t & 63;
  int bxx = blockIdx.x;            // 0..47
  int jh = bxx & 1;                // j-half
  int lh = bxx >> 1;               // 0..23: l = lh>>1, w-half = lh&1
  int l = lh >> 1, wh = lh & 1;
  int nloc = blockIdx.y;
  int n = n0 + nloc;
  const short* xbase = xb + (size_t)(n * 12 + l) * 512 * 64;
  short8 af[4][2];
  for (int q = 0; q < 4; ++q)
    for (int ks = 0; ks < 2; ++ks) {
      int wrow = wh * 256 + wv * 64 + q * 16 + (lane & 15);
      int cblk = ks * 4 + (lane >> 4);
      af[q][ks] = *(const short8*)(xbase + (size_t)wrow * 64 + cblk * 8);
    }
  int lanebase = (lane & 15) * 12 + l;
  int kt_off = wh * 4 + wv;
  const short* wbase = Wbf + (lane >> 4) * 128 + (lane & 15) * 8;
  for (int j = jh * 18; j < jh * 18 + 18; ++j) {
    int k = j >> 2, jm = j & 3;
    const short* wp = wbase + (size_t)((k * 4 + jm) * 2) * 512;  // ks stride 512
    short8 bw0 = *(const short8*)(wp);
    short8 bw1 = *(const short8*)(wp + 512);
    f32x4 acc[4];
    for (int q = 0; q < 4; ++q) {
      acc[q] = (f32x4){0.f, 0.f, 0.f, 0.f};
      acc[q] = __builtin_amdgcn_mfma_f32_16x16x32_bf16(af[q][0], bw0, acc[q], 0, 0, 0);
      acc[q] = __builtin_amdgcn_mfma_f32_16x16x32_bf16(af[q][1], bw1, acc[q], 0, 0, 0);
    }
    int zr = jm * 192 + lanebase;
    int pr = zr >> 7, rr = zr & 127;
    size_t tbase = ((size_t)(nloc * 6 + pr) * PANEL_TILES + k * 8 + kt_off) * TILE_SHORTS
                 + rr * 64;
    for (int q = 0; q < 4; ++q) {
      int c4 = q * 16 + (lane >> 4) * 4;
      size_t idx = tbase + ((((c4 >> 3) ^ (zr & 7)) << 3) | (c4 & 7));
      short4v s;
      for (int e = 0; e < 4; ++e) s[e] = f2bf(acc[q][e]);
      *(short4v*)(Zt + idx) = s;
    }
  }
}

// ---------- kernel 4: big batched GEMM (R14-proven config) ----------
// Block: 128 rowM x 64 v, 4 waves each 32x64. Per stage: A 16KB + B 8KB = 6
// gloads/wave. LDS 48KB -> 3 blocks/CU; counted vmcnt(6); 2 barriers/step.
__global__ __launch_bounds__(256) void biggemm_kernel(const short* __restrict__ Zt,
    const short* __restrict__ Mt, const float* __restrict__ bvec,
    float* __restrict__ out, int n0) {
  int tid = threadIdx.x, wv = tid >> 6, lane = tid & 63;
  int nwg = gridDim.x;
  int b = blockIdx.x;
  int swz = (b & 7) * (nwg >> 3) + (b >> 3);   // nwg = 48*cn, always % 8 == 0
  int bx = swz & 7;                // v-tile of 64, fastest (8 siblings share A)
  int rest = swz >> 3;
  int by = rest % 6;
  int bz = rest / 6;
  int v0    = bx * 64;
  int rowM0 = by * 128;
  int n = n0 + bz;
  __shared__ short As[2][TILE_SHORTS];       // 2 x 16 KiB
  __shared__ short Bs[2][TILE_SHORTS / 2];   // 2 x 8 KiB  (48 KiB total)
  f32x4 acc[2][4];
  for (int i = 0; i < 2; ++i)
    for (int j = 0; j < 4; ++j) acc[i][j] = (f32x4){0.f, 0.f, 0.f, 0.f};
  const char* Apanel = (const char*)(Zt + (size_t)(bz * 6 + by) * PANEL_TILES * TILE_SHORTS);
  const char* Bpanel = (const char*)(Mt + (size_t)(bx >> 1) * PANEL_TILES * TILE_SHORTS)
                     + (bx & 1) * 8192;

  // step -> kt: k=0 B-rows identity; only kt == bx nonzero for this v-range.
  auto ktmap = [&](int s) { return (s == 0) ? bx : (s + 7); };

  auto STAGE = [&](int p, int kt) {
    const char* a  = Apanel + (size_t)kt * (TILE_SHORTS * 2);
    const char* bb = Bpanel + (size_t)kt * (TILE_SHORTS * 2);
#pragma unroll
    for (int cc = 0; cc < 4; ++cc) {
      int chunk = cc * 4 + wv;                 // 0..15
      int off = chunk * 1024 + lane * 16;      // linear 1KB per instruction
      gload_lds16(a + off, (char*)As[p] + chunk * 1024);
    }
#pragma unroll
    for (int cc = 0; cc < 2; ++cc) {
      int chunk = cc * 4 + wv;                 // 0..7
      int off = chunk * 1024 + lane * 16;
      gload_lds16(bb + off, (char*)Bs[p] + chunk * 1024);
    }
  };

  // prologue: two K-steps in flight (12 outstanding gloads/wave)
  STAGE(0, ktmap(0));
  STAGE(1, ktmap(1));

  for (int s = 0; s < NSTEP; ++s) {
    int d = s & 1;
    if (s < NSTEP - 1) {
      asm volatile("s_waitcnt vmcnt(6)" ::: "memory");
    } else {
      asm volatile("s_waitcnt vmcnt(0)" ::: "memory");
    }
    __builtin_amdgcn_sched_barrier(0);
    __builtin_amdgcn_s_barrier();          // dbuf[d] visible to all waves

    short8 af[2][2], bf[2][4];
#pragma unroll
    for (int kk = 0; kk < 2; ++kk) {
      int cbyte = kk * 64 + (lane >> 4) * 16;
#pragma unroll
      for (int mi = 0; mi < 2; ++mi) {
        int r = wv * 32 + mi * 16 + (lane & 15);
        af[kk][mi] = *(const short8*)((const char*)As[d] + r * 128 + (cbyte ^ ((r & 7) << 4)));
      }
#pragma unroll
      for (int ni = 0; ni < 4; ++ni) {
        int r2 = ni * 16 + (lane & 15);
        bf[kk][ni] = *(const short8*)((const char*)Bs[d] + r2 * 128 + (cbyte ^ ((r2 & 7) << 4)));
      }
    }
    asm volatile("s_waitcnt lgkmcnt(0)" ::: "memory");   // this wave's reads done
    __builtin_amdgcn_sched_barrier(0);
    __builtin_amdgcn_s_barrier();          // ALL waves' reads done -> dbuf[d] dead

    if (s + 2 < NSTEP) STAGE(d, ktmap(s + 2));

    __builtin_amdgcn_s_setprio(1);
#pragma unroll
    for (int kk = 0; kk < 2; ++kk)
#pragma unroll
      for (int mi = 0; mi < 2; ++mi)
#pragma unroll
        for (int ni = 0; ni < 4; ++ni)
          acc[mi][ni] = __builtin_amdgcn_mfma_f32_16x16x32_bf16(af[kk][mi], bf[kk][ni],
                                                                acc[mi][ni], 0, 0, 0);
    __builtin_amdgcn_s_setprio(0);
  }

  for (int mi = 0; mi < 2; ++mi) {
    for (int r = 0; r < 4; ++r) {
      int gm = rowM0 + wv * 32 + mi * 16 + (lane >> 4) * 4 + r;   // = o*12+l
      int o = gm / 12, l = gm - o * 12;
      float bo = bvec[o];
      size_t obase = (((size_t)n * 64 + o) * 500) * 12 + l;
      for (int ni = 0; ni < 4; ++ni) {
        int v = v0 + ni * 16 + (lane & 15);
        if (v < 500) out[obase + (size_t)v * 12] = acc[mi][ni][r] + bo;
      }
    }
  }
}

// ---------- host ----------
extern "C" void kernel_launch(void* const* d_in, const int* in_sizes, int n_in,
                              void* d_out, int out_size, void* d_ws, size_t ws_size,
                              hipStream_t stream) {
  const float* x   = (const float*)d_in[0];
  const float* adj = (const float*)d_in[1];
  const float* W   = (const float*)d_in[2];
  const float* bv  = (const float*)d_in[3];
  float* out = (float*)d_out;
  char* ws = (char*)d_ws;

  size_t off = 0;
  float* Mpow0 = (float*)(ws + off); off += (size_t)512 * 512 * 4;
  float* Mpow1 = (float*)(ws + off); off += (size_t)512 * 512 * 4;
  short* M1T   = (short*)(ws + off); off += (size_t)512 * 512 * 2;
  short* Wbf   = (short*)(ws + off); off += (size_t)36864 * 2;       // 72 KiB
  short* Mt    = (short*)(ws + off); off += (size_t)4 * PANEL_TILES * TILE_SHORTS * 2;
  short* xb    = (short*)(ws + off); off += (size_t)64 * 12 * 512 * 64 * 2;  // 50.3 MB
  short* Zt    = (short*)(ws + off);
  size_t per_n = (size_t)6 * PANEL_TILES * TILE_SHORTS * 2;          // 7,077,888 B
  int nchunk = 1;
  if (ws_size > off) {
    size_t a = (ws_size - off) / per_n;
    nchunk = (a >= 16) ? 16 : (a < 1 ? 1 : (int)a);   // 16 -> Z chunk 113 MB, L3-fits
  }

  hipLaunchKernelGGL(initM_kernel, dim3(1024), dim3(256), 0, stream, adj, Mpow0, Mt, M1T);
  hipLaunchKernelGGL(wprep_kernel, dim3(144), dim3(256), 0, stream, W, Wbf);
  const float* src = Mpow0; float* dst = Mpow1;
  for (int k = 2; k <= 8; ++k) {
    hipLaunchKernelGGL(powstep_kernel, dim3(256), dim3(256), 0, stream, src, M1T, dst, Mt, k);
    float* t = dst; dst = (float*)src; src = t;
  }
  hipLaunchKernelGGL(xpose_kernel, dim3(16, 64), dim3(256), 0, stream, x, xb);
  for (int n0 = 0; n0 < 64; n0 += nchunk) {
    int cn = (64 - n0) < nchunk ? (64 - n0) : nchunk;
    hipLaunchKernelGGL(zbuild_kernel, dim3(48, cn), dim3(256), 0, stream, xb, Wbf, Zt, n0);
    hipLaunchKernelGGL(biggemm_kernel, dim3(48 * cn), dim3(256), 0, stream, Zt, Mt, bv, out, n0);
  }
}

// Round 17
// 508.604 us; speedup vs baseline: 1.7470x; 1.0014x over previous
//
#include <hip/hip_runtime.h>
#include <hip/hip_bf16.h>
#include <stdint.h>

// ---------- types ----------
typedef __attribute__((ext_vector_type(8))) short short8;   // 8 bf16
typedef __attribute__((ext_vector_type(4))) short short4v;  // 4 bf16 (8 B)
typedef __attribute__((ext_vector_type(4))) float f32x4;
typedef __attribute__((ext_vector_type(4))) float fvec4;

__device__ __forceinline__ short f2bf(float f) {
  unsigned u = __builtin_bit_cast(unsigned, f);
  unsigned r = u + 0x7fffu + ((u >> 16) & 1u);
  return (short)(r >> 16);
}

__device__ __forceinline__ void gload_lds16(const void* g, void* l) {
  __builtin_amdgcn_global_load_lds(
      (const __attribute__((address_space(1))) void*)g,
      (__attribute__((address_space(3))) void*)l, 16, 0, 0);
}

// Problem: x[64,64,500,12], adj[500,500], W[64,576], b[64]; out[64,64,500,12]
// M = I + 0.125*adj. K-axis (k,w): 9*512 = 4608 = 72 kt-tiles of 64.
// Tiled operand layout: tile = [128 r][64 c] bf16, 16 KB, XOR pre-swizzled.
// nchunk=16 keeps the Z chunk (113 MB) L3-resident (R10: worth ~140us).
// This round: biggemm pairs TWO n per block (shared B tile): per-output
// B-reads, barriers, vmcnt stalls halved. LDS 80KB -> 2 blocks/CU;
// __launch_bounds__(256,2) prevents the R15-style spill at ~155 VGPR.
#define VP   512
#define TILE_SHORTS 8192
#define PANEL_TILES 72
#define NSTEP 65

__device__ __forceinline__ int tswz(int r, int c) {
  return r * 64 + ((((c >> 3) ^ (r & 7)) << 3) | (c & 7));
}

// ---------- kernel 1: M^0 (I), M^1 tiles, fp32 master, bf16 M1^T ----------
__global__ __launch_bounds__(256) void initM_kernel(const float* __restrict__ adj,
    float* __restrict__ Mpow, short* __restrict__ Mt, short* __restrict__ M1T) {
  int idx = blockIdx.x * 256 + threadIdx.x;
  int v = idx >> 9, w = idx & 511;
  float m = 0.f;
  if (v < 500 && w < 500) m = 0.125f * adj[v * 500 + w] + (v == w ? 1.f : 0.f);
  Mpow[idx] = m;
  M1T[(size_t)w * VP + v] = f2bf(m);
  int bx = v >> 7, r = v & 127, c = w & 63;
  int kt0 = (w >> 6), kt1 = 8 + (w >> 6);
  Mt[(size_t)(bx * PANEL_TILES + kt0) * TILE_SHORTS + tswz(r, c)] =
      f2bf((v == w && v < 500) ? 1.f : 0.f);
  Mt[(size_t)(bx * PANEL_TILES + kt1) * TILE_SHORTS + tswz(r, c)] = f2bf(m);
}

// ---------- kernel 1.5: W -> bf16 fragment-layout pack ----------
__global__ __launch_bounds__(256) void wprep_kernel(const float* __restrict__ W,
    short* __restrict__ Wbf) {
  int idx = blockIdx.x * 256 + threadIdx.x;   // 0..36863 (grid 144)
  int e = idx & 7, l4 = (idx >> 3) & 15, h = (idx >> 7) & 3;
  int ks = (idx >> 9) & 1, jm = (idx >> 10) & 3, k = idx >> 12;
  int o = jm * 16 + l4, c = k * 64 + ks * 32 + h * 8 + e;
  Wbf[idx] = f2bf(W[o * 576 + c]);
}

// ---------- kernel 2: P = src * M1 (B-frag = one short8 from M1T) ----------
__global__ __launch_bounds__(256) void powstep_kernel(const float* __restrict__ src,
    const short* __restrict__ M1T, float* __restrict__ dst,
    short* __restrict__ Mt, int kslice) {
  int tid = threadIdx.x, wv = tid >> 6, lane = tid & 63;
  int tile = blockIdx.x * 4 + wv;
  int tv = tile >> 5, tw = tile & 31;
  int row  = tv * 16 + (lane & 15);
  int colw = tw * 16 + (lane & 15);
  int kgrp = (lane >> 4) * 8;
  const short* mcol = M1T + (size_t)colw * VP;
  f32x4 acc = {0.f, 0.f, 0.f, 0.f};
  for (int k0 = 0; k0 < 512; k0 += 32) {
    int kc = k0 + kgrp;
    fvec4 f0 = *(const fvec4*)&src[row * VP + kc];
    fvec4 f1 = *(const fvec4*)&src[row * VP + kc + 4];
    short8 a;
    for (int t = 0; t < 4; ++t) { a[t] = f2bf(f0[t]); a[4 + t] = f2bf(f1[t]); }
    short8 b = *(const short8*)&mcol[kc];
    acc = __builtin_amdgcn_mfma_f32_16x16x32_bf16(a, b, acc, 0, 0, 0);
  }
  for (int r = 0; r < 4; ++r) {
    int i = (lane >> 4) * 4 + r;
    int vv = tv * 16 + i;
    float val = acc[r];
    dst[vv * VP + colw] = val;
    int bx = vv >> 7, rr = vv & 127, c = colw & 63;
    int kt = kslice * 8 + (colw >> 6);
    Mt[(size_t)(bx * PANEL_TILES + kt) * TILE_SHORTS + tswz(rr, c)] = f2bf(val);
  }
}

// ---------- kernel 2.5: x transpose: x[n,c,w,l] f32 -> xb[n,l,w512,c64] bf16 ----
__global__ __launch_bounds__(256) void xpose_kernel(const float* __restrict__ x,
    short* __restrict__ xb) {
  int t = threadIdx.x, wv = t >> 6, lane = t & 63;
  int p  = blockIdx.x & 1;          // c-half
  int w0 = (blockIdx.x >> 1) * 64;  // 0..448
  int n  = blockIdx.y;
  const float* xs = x + (size_t)n * 64 * 6000;
  __shared__ short xl[32 * 770];
  for (int ci = 0; ci < 8; ++ci) {
    int crow = wv * 8 + ci;
    int c = p * 32 + crow;
    for (int i = 0; i < 3; ++i) {
      int wl = (i * 64 + lane) * 4;
      int gwl = w0 * 12 + wl;
      fvec4 v = {0.f, 0.f, 0.f, 0.f};
      if (gwl + 3 < 6000) {
        v = *(const fvec4*)&xs[(size_t)c * 6000 + gwl];
      } else {
        for (int e = 0; e < 4; ++e)
          if (gwl + e < 6000) v[e] = xs[(size_t)c * 6000 + gwl + e];
      }
      for (int e = 0; e < 4; ++e) xl[crow * 770 + wl + e] = f2bf(v[e]);
    }
  }
  __syncthreads();
  for (int i = 0; i < 12; ++i) {
    int ct = i * 256 + t;
    int bl = ct & 3;
    int w_l = (ct >> 2) & 63;
    int l = ct >> 8;
    short8 s;
    for (int j = 0; j < 8; ++j)
      s[j] = xl[(bl * 8 + j) * 770 + w_l * 12 + l];
    size_t dst = ((size_t)(n * 12 + l) * 512 + w0 + w_l) * 64 + (p * 4 + bl) * 8;
    *(short8*)(xb + dst) = s;
  }
}

// ---------- kernel 3: Z build — register GEMM, pre-packed W, j-split ----------
__global__ __launch_bounds__(256) void zbuild_kernel(const short* __restrict__ xb,
    const short* __restrict__ Wbf, short* __restrict__ Zt, int n0) {
  int t = threadIdx.x, wv = t >> 6, lane = t & 63;
  int bxx = blockIdx.x;            // 0..47
  int jh = bxx & 1;                // j-half
  int lh = bxx >> 1;               // 0..23: l = lh>>1, w-half = lh&1
  int l = lh >> 1, wh = lh & 1;
  int nloc = blockIdx.y;
  int n = n0 + nloc;
  const short* xbase = xb + (size_t)(n * 12 + l) * 512 * 64;
  short8 af[4][2];
  for (int q = 0; q < 4; ++q)
    for (int ks = 0; ks < 2; ++ks) {
      int wrow = wh * 256 + wv * 64 + q * 16 + (lane & 15);
      int cblk = ks * 4 + (lane >> 4);
      af[q][ks] = *(const short8*)(xbase + (size_t)wrow * 64 + cblk * 8);
    }
  int lanebase = (lane & 15) * 12 + l;
  int kt_off = wh * 4 + wv;
  const short* wbase = Wbf + (lane >> 4) * 128 + (lane & 15) * 8;
  for (int j = jh * 18; j < jh * 18 + 18; ++j) {
    int k = j >> 2, jm = j & 3;
    const short* wp = wbase + (size_t)((k * 4 + jm) * 2) * 512;  // ks stride 512
    short8 bw0 = *(const short8*)(wp);
    short8 bw1 = *(const short8*)(wp + 512);
    f32x4 acc[4];
    for (int q = 0; q < 4; ++q) {
      acc[q] = (f32x4){0.f, 0.f, 0.f, 0.f};
      acc[q] = __builtin_amdgcn_mfma_f32_16x16x32_bf16(af[q][0], bw0, acc[q], 0, 0, 0);
      acc[q] = __builtin_amdgcn_mfma_f32_16x16x32_bf16(af[q][1], bw1, acc[q], 0, 0, 0);
    }
    int zr = jm * 192 + lanebase;
    int pr = zr >> 7, rr = zr & 127;
    size_t tbase = ((size_t)(nloc * 6 + pr) * PANEL_TILES + k * 8 + kt_off) * TILE_SHORTS
                 + rr * 64;
    for (int q = 0; q < 4; ++q) {
      int c4 = q * 16 + (lane >> 4) * 4;
      size_t idx = tbase + ((((c4 >> 3) ^ (zr & 7)) << 3) | (c4 & 7));
      short4v s;
      for (int e = 0; e < 4; ++e) s[e] = f2bf(acc[q][e]);
      *(short4v*)(Zt + idx) = s;
    }
  }
}

// ---------- kernel 4: big batched GEMM (n-paired, shared B) ----------
// Block: 2 x (128 rowM x 64 v) for n-pair, 4 waves each 32x(64v x2n).
// Per stage: A1 16KB + A2 16KB + B 8KB = 10 gloads/wave. LDS 80KB -> 2/CU.
// Counted vmcnt(10); 2 barriers/step; 32 MFMA/step/wave.
__global__ __launch_bounds__(256, 2) void biggemm_kernel(const short* __restrict__ Zt,
    const short* __restrict__ Mt, const float* __restrict__ bvec,
    float* __restrict__ out, int n0) {
  int tid = threadIdx.x, wv = tid >> 6, lane = tid & 63;
  int nwg = gridDim.x;
  int b = blockIdx.x;
  int swz = (b & 7) * (nwg >> 3) + (b >> 3);   // nwg = 24*cn, % 8 == 0 for even cn
  int bx = swz & 7;                // v-tile of 64, fastest (8 siblings share A)
  int rest = swz >> 3;
  int by = rest % 6;
  int bzp = rest / 6;              // n-pair index
  int v0    = bx * 64;
  int rowM0 = by * 128;
  int n1 = n0 + bzp * 2;
  int n2 = n1 + 1;
  __shared__ short As1[2][TILE_SHORTS];      // 2 x 16 KiB
  __shared__ short As2[2][TILE_SHORTS];      // 2 x 16 KiB
  __shared__ short Bs[2][TILE_SHORTS / 2];   // 2 x 8 KiB   (80 KiB total)
  f32x4 acc1[2][4], acc2[2][4];
  for (int i = 0; i < 2; ++i)
    for (int j = 0; j < 4; ++j) {
      acc1[i][j] = (f32x4){0.f, 0.f, 0.f, 0.f};
      acc2[i][j] = (f32x4){0.f, 0.f, 0.f, 0.f};
    }
  const char* Apanel1 = (const char*)(Zt + (size_t)((bzp * 2)     * 6 + by) * PANEL_TILES * TILE_SHORTS);
  const char* Apanel2 = (const char*)(Zt + (size_t)((bzp * 2 + 1) * 6 + by) * PANEL_TILES * TILE_SHORTS);
  const char* Bpanel = (const char*)(Mt + (size_t)(bx >> 1) * PANEL_TILES * TILE_SHORTS)
                     + (bx & 1) * 8192;

  // step -> kt: k=0 B-rows identity; only kt == bx nonzero for this v-range.
  auto ktmap = [&](int s) { return (s == 0) ? bx : (s + 7); };

  auto STAGE = [&](int p, int kt) {
    const char* a1 = Apanel1 + (size_t)kt * (TILE_SHORTS * 2);
    const char* a2 = Apanel2 + (size_t)kt * (TILE_SHORTS * 2);
    const char* bb = Bpanel  + (size_t)kt * (TILE_SHORTS * 2);
#pragma unroll
    for (int cc = 0; cc < 4; ++cc) {
      int chunk = cc * 4 + wv;                 // 0..15
      int off = chunk * 1024 + lane * 16;      // linear 1KB per instruction
      gload_lds16(a1 + off, (char*)As1[p] + chunk * 1024);
      gload_lds16(a2 + off, (char*)As2[p] + chunk * 1024);
    }
#pragma unroll
    for (int cc = 0; cc < 2; ++cc) {
      int chunk = cc * 4 + wv;                 // 0..7
      int off = chunk * 1024 + lane * 16;
      gload_lds16(bb + off, (char*)Bs[p] + chunk * 1024);
    }
  };

  // prologue: two K-steps in flight (20 outstanding gloads/wave)
  STAGE(0, ktmap(0));
  STAGE(1, ktmap(1));

  for (int s = 0; s < NSTEP; ++s) {
    int d = s & 1;
    if (s < NSTEP - 1) {
      asm volatile("s_waitcnt vmcnt(10)" ::: "memory");
    } else {
      asm volatile("s_waitcnt vmcnt(0)" ::: "memory");
    }
    __builtin_amdgcn_sched_barrier(0);
    __builtin_amdgcn_s_barrier();          // dbuf[d] visible to all waves

    short8 af1[2][2], af2[2][2], bf[2][4];
#pragma unroll
    for (int kk = 0; kk < 2; ++kk) {
      int cbyte = kk * 64 + (lane >> 4) * 16;
#pragma unroll
      for (int mi = 0; mi < 2; ++mi) {
        int r = wv * 32 + mi * 16 + (lane & 15);
        int o8 = r * 128 + (cbyte ^ ((r & 7) << 4));
        af1[kk][mi] = *(const short8*)((const char*)As1[d] + o8);
        af2[kk][mi] = *(const short8*)((const char*)As2[d] + o8);
      }
#pragma unroll
      for (int ni = 0; ni < 4; ++ni) {
        int r2 = ni * 16 + (lane & 15);
        bf[kk][ni] = *(const short8*)((const char*)Bs[d] + r2 * 128 + (cbyte ^ ((r2 & 7) << 4)));
      }
    }
    asm volatile("s_waitcnt lgkmcnt(0)" ::: "memory");   // this wave's reads done
    __builtin_amdgcn_sched_barrier(0);
    __builtin_amdgcn_s_barrier();          // ALL waves' reads done -> dbuf[d] dead

    if (s + 2 < NSTEP) STAGE(d, ktmap(s + 2));

    __builtin_amdgcn_s_setprio(1);
#pragma unroll
    for (int kk = 0; kk < 2; ++kk)
#pragma unroll
      for (int mi = 0; mi < 2; ++mi)
#pragma unroll
        for (int ni = 0; ni < 4; ++ni) {
          acc1[mi][ni] = __builtin_amdgcn_mfma_f32_16x16x32_bf16(af1[kk][mi], bf[kk][ni],
                                                                 acc1[mi][ni], 0, 0, 0);
          acc2[mi][ni] = __builtin_amdgcn_mfma_f32_16x16x32_bf16(af2[kk][mi], bf[kk][ni],
                                                                 acc2[mi][ni], 0, 0, 0);
        }
    __builtin_amdgcn_s_setprio(0);
  }

  for (int mi = 0; mi < 2; ++mi) {
    for (int r = 0; r < 4; ++r) {
      int gm = rowM0 + wv * 32 + mi * 16 + (lane >> 4) * 4 + r;   // = o*12+l
      int o = gm / 12, l = gm - o * 12;
      float bo = bvec[o];
      size_t ob1 = (((size_t)n1 * 64 + o) * 500) * 12 + l;
      size_t ob2 = (((size_t)n2 * 64 + o) * 500) * 12 + l;
      for (int ni = 0; ni < 4; ++ni) {
        int v = v0 + ni * 16 + (lane & 15);
        if (v < 500) {
          out[ob1 + (size_t)v * 12] = acc1[mi][ni][r] + bo;
          out[ob2 + (size_t)v * 12] = acc2[mi][ni][r] + bo;
        }
      }
    }
  }
}

// ---------- host ----------
extern "C" void kernel_launch(void* const* d_in, const int* in_sizes, int n_in,
                              void* d_out, int out_size, void* d_ws, size_t ws_size,
                              hipStream_t stream) {
  const float* x   = (const float*)d_in[0];
  const float* adj = (const float*)d_in[1];
  const float* W   = (const float*)d_in[2];
  const float* bv  = (const float*)d_in[3];
  float* out = (float*)d_out;
  char* ws = (char*)d_ws;

  size_t off = 0;
  float* Mpow0 = (float*)(ws + off); off += (size_t)512 * 512 * 4;
  float* Mpow1 = (float*)(ws + off); off += (size_t)512 * 512 * 4;
  short* M1T   = (short*)(ws + off); off += (size_t)512 * 512 * 2;
  short* Wbf   = (short*)(ws + off); off += (size_t)36864 * 2;       // 72 KiB
  short* Mt    = (short*)(ws + off); off += (size_t)4 * PANEL_TILES * TILE_SHORTS * 2;
  short* xb    = (short*)(ws + off); off += (size_t)64 * 12 * 512 * 64 * 2;  // 50.3 MB
  short* Zt    = (short*)(ws + off);
  size_t per_n = (size_t)6 * PANEL_TILES * TILE_SHORTS * 2;          // 7,077,888 B
  int nchunk = 2;
  if (ws_size > off) {
    size_t a = (ws_size - off) / per_n;
    nchunk = (a >= 16) ? 16 : (a < 2 ? 2 : (int)a);
    nchunk &= ~1;                                   // n-pairing needs even
    if (nchunk < 2) nchunk = 2;
  }

  hipLaunchKernelGGL(initM_kernel, dim3(1024), dim3(256), 0, stream, adj, Mpow0, Mt, M1T);
  hipLaunchKernelGGL(wprep_kernel, dim3(144), dim3(256), 0, stream, W, Wbf);
  const float* src = Mpow0; float* dst = Mpow1;
  for (int k = 2; k <= 8; ++k) {
    hipLaunchKernelGGL(powstep_kernel, dim3(256), dim3(256), 0, stream, src, M1T, dst, Mt, k);
    float* t = dst; dst = (float*)src; src = t;
  }
  hipLaunchKernelGGL(xpose_kernel, dim3(16, 64), dim3(256), 0, stream, x, xb);
  for (int n0 = 0; n0 < 64; n0 += nchunk) {
    int cn = (64 - n0) < nchunk ? (64 - n0) : nchunk;
    hipLaunchKernelGGL(zbuild_kernel, dim3(48, cn), dim3(256), 0, stream, xb, Wbf, Zt, n0);
    hipLaunchKernelGGL(biggemm_kernel, dim3(24 * cn), dim3(256), 0, stream, Zt, Mt, bv, out, n0);
  }
}